// Round 13
// baseline (154.668 us; speedup 1.0000x reference)
//
#include <hip/hip_runtime.h>
#include <stdint.h>

typedef unsigned short ushort_t;
typedef __attribute__((ext_vector_type(8))) short short8;
typedef __attribute__((ext_vector_type(4))) float f32x4;
typedef __attribute__((ext_vector_type(16))) float f32x16;
typedef __attribute__((ext_vector_type(4))) uint32_t u32x4;
typedef __attribute__((ext_vector_type(2))) uint32_t u32x2;

#define MFMA16 __builtin_amdgcn_mfma_f32_16x16x32_bf16
#define MFMA32 __builtin_amdgcn_mfma_f32_32x32x16_bf16

// global->LDS direct (16B/lane); dest = wave-uniform base + lane*16 (m97/m104)
#define GLOAD_LDS16(gp, lp)                                                  \
    __builtin_amdgcn_global_load_lds(                                        \
        (const __attribute__((address_space(1))) void*)(gp),                 \
        (__attribute__((address_space(3))) void*)(lp), 16, 0, 0)

__device__ inline ushort_t f2bf(float f) {
    union { float f; uint32_t u; } x; x.f = f;
    uint32_t r = x.u + 0x7FFFu + ((x.u >> 16) & 1u);
    return (ushort_t)(r >> 16);
}
// single-instruction packed f32->bf16 (RNE), gfx950
__device__ inline uint32_t cvtpk(float lo, float hi) {
    uint32_t r;
    asm("v_cvt_pk_bf16_f32 %0, %1, %2" : "=v"(r) : "v"(lo), "v"(hi));
    return r;
}
#define EXP2R __builtin_amdgcn_exp2f   // raw v_exp_f32

// ---------------- fused prep: conv_x + prep_wqkv + prep_w3 ----------------
__global__ __launch_bounds__(256) void prep_all(const float* __restrict__ x,
                                                const float* __restrict__ wl_in,
                                                const float* __restrict__ wg_in,
                                                const float* __restrict__ bl_in,
                                                const float* __restrict__ bg_in,
                                                const float* __restrict__ wl_out,
                                                const float* __restrict__ wg_out,
                                                const float* __restrict__ bl_out,
                                                const float* __restrict__ bg_out,
                                                const float* __restrict__ gate,
                                                ushort_t* __restrict__ xb,
                                                ushort_t* __restrict__ Wqkv,
                                                float* __restrict__ bqkv,
                                                ushort_t* __restrict__ W3,
                                                float* __restrict__ b3) {
    const float QSC = 0.125f * 1.44269504089f;   // fold score-scale * log2(e) into Q
    int gid = blockIdx.x * 256 + threadIdx.x;
    if (gid < 262144) {                       // x -> bf16 (4096*512/8)
        int base = gid * 8;
        short8 v;
#pragma unroll
        for (int j = 0; j < 8; j++) v[j] = (short)f2bf(x[base + j]);
        *reinterpret_cast<short8*>(&xb[base]) = v;
    } else if (gid < 458752) {                // Wqkv (3072*512/8)
        int g2 = gid - 262144;
        int base = g2 * 8;
        short8 v;
#pragma unroll
        for (int j = 0; j < 8; j++) {
            int e = base + j;
            int n = e >> 9;
            int nm = n >= 1536 ? n - 1536 : n;
            float sc = (nm < 512) ? QSC : 1.0f;
            float f = (e < 1536 * 512) ? wl_in[e] : wg_in[e - 1536 * 512];
            v[j] = (short)f2bf(f * sc);
        }
        *reinterpret_cast<short8*>(&Wqkv[base]) = v;
        if (g2 < 3072) {
            int nm = g2 >= 1536 ? g2 - 1536 : g2;
            float sc = (nm < 512) ? QSC : 1.0f;
            bqkv[g2] = ((g2 < 1536) ? bl_in[g2] : bg_in[g2 - 1536]) * sc;
        }
    } else {                                  // W3 (512*1024/8)
        int g2 = gid - 458752;
        float gv = gate[0];
        int base = g2 * 8;
        short8 v;
#pragma unroll
        for (int j = 0; j < 8; j++) {
            int e = base + j;
            int n = e >> 10, k = e & 1023;
            float f = (k < 512) ? gv * wl_out[n * 512 + k]
                                : (1.0f - gv) * wg_out[n * 512 + (k - 512)];
            v[j] = (short)f2bf(f);
        }
        *reinterpret_cast<short8*>(&W3[base]) = v;
        if (g2 < 512) b3[g2] = gv * bl_out[g2] + (1.0f - gv) * bg_out[g2];
    }
}

// ---------------- GEMM: C[M][N] = A[M][K] * B[N][K]^T + bias ----------------
// m97-style staging: global_load_lds dwordx4, LINEAR (unpadded) LDS tiles.
// FUSE_VT: V-range columns (n in [1024,1536)+[2560,3072)) go to VT[br][dfull][l].
template<int NI, bool OUT_BF16, bool FUSE_VT>
__global__ __launch_bounds__(256) void gemm_bt(const ushort_t* __restrict__ A,
                                               const ushort_t* __restrict__ B,
                                               const float* __restrict__ bias,
                                               void* __restrict__ Cout,
                                               ushort_t* __restrict__ VTout,
                                               int M, int N, int K) {
    constexpr int TN = NI * 32;
    __shared__ __align__(16) ushort_t As[128 * 64];
    __shared__ __align__(16) ushort_t Bs[TN * 64];
    const int tid = threadIdx.x;
    const int lane = tid & 63, wid = tid >> 6;
    const int g = lane >> 4, c = lane & 15;
    const int wm = wid >> 1, wn = wid & 1;
    const int bm = blockIdx.x, bn = blockIdx.y;

    f32x4 acc[4][NI];
#pragma unroll
    for (int i = 0; i < 4; i++)
#pragma unroll
        for (int j = 0; j < NI; j++) acc[i][j] = f32x4{0.f, 0.f, 0.f, 0.f};

    for (int ks = 0; ks < K; ks += 64) {
#pragma unroll
        for (int it = 0; it < 4; it++) {           // A: 128x64 = 1024 chunks
            int idx = it * 256 + tid;
            int r = idx >> 3, ch = idx & 7;
            GLOAD_LDS16(&A[(size_t)(bm * 128 + r) * K + ks + ch * 8],
                        &As[(size_t)(idx & ~63) * 8]);
        }
#pragma unroll
        for (int it = 0; it < TN / 32; it++) {     // B: TN x 64
            int idx = it * 256 + tid;
            int r = idx >> 3, ch = idx & 7;
            GLOAD_LDS16(&B[(size_t)(bn * TN + r) * K + ks + ch * 8],
                        &Bs[(size_t)(idx & ~63) * 8]);
        }
        __syncthreads();                           // drains vmcnt (compiler)
#pragma unroll
        for (int kk = 0; kk < 2; kk++) {
            short8 a[4], b[NI];
#pragma unroll
            for (int mi = 0; mi < 4; mi++)
                a[mi] = *reinterpret_cast<const short8*>(&As[(wm * 64 + mi * 16 + c) * 64 + kk * 32 + g * 8]);
#pragma unroll
            for (int ni = 0; ni < NI; ni++)
                b[ni] = *reinterpret_cast<const short8*>(&Bs[(wn * (NI * 16) + ni * 16 + c) * 64 + kk * 32 + g * 8]);
#pragma unroll
            for (int mi = 0; mi < 4; mi++)
#pragma unroll
                for (int ni = 0; ni < NI; ni++)
                    acc[mi][ni] = MFMA16(a[mi], b[ni], acc[mi][ni], 0, 0, 0);
        }
        __syncthreads();
    }
#pragma unroll
    for (int mi = 0; mi < 4; mi++) {
#pragma unroll
        for (int ni = 0; ni < NI; ni++) {
            int n = bn * TN + wn * (NI * 16) + ni * 16 + c;
            float bv = bias[n];
            float v0 = acc[mi][ni][0] + bv;
            float v1 = acc[mi][ni][1] + bv;
            float v2 = acc[mi][ni][2] + bv;
            float v3 = acc[mi][ni][3] + bv;
            int m0 = bm * 128 + wm * 64 + mi * 16 + g * 4;
            bool isV = FUSE_VT && (n >= 1024) && (n < 1536 || n >= 2560);
            if (isV) {
                int br = n >= 1536 ? 1 : 0;
                int dfull = (br ? n - 1536 : n) - 1024;        // 0..511
                int bb = m0 >> 11, l0 = m0 & 2047;
                u32x2 pk;
                pk[0] = cvtpk(v0, v1);
                pk[1] = cvtpk(v2, v3);
                *reinterpret_cast<u32x2*>(
                    &VTout[(size_t)br * 2097152 + ((size_t)bb * 512 + dfull) * 2048 + l0]) = pk;
            } else {
                float vv[4] = {v0, v1, v2, v3};
#pragma unroll
                for (int r = 0; r < 4; r++) {
                    int m = m0 + r;
                    if (OUT_BF16) ((ushort_t*)Cout)[(size_t)m * N + n] = f2bf(vv[r]);
                    else          ((float*)Cout)[(size_t)m * N + n] = vv[r];
                }
            }
        }
    }
}

// ---------------- attention: 8 waves, 64 q-rows, 4-way kt-split, KVBLK=32 ----------------
// wave w: row-group rg=w&1 (32 rows), kt-stream kg=w>>1 (kt = kt0+kg, step 4, 32-row tiles).
// Stream LDS: K[32][72] + V[64][36] = 9216 B; pool 36.9KB -> 3-4 WGs/CU.
// Two-level register merge (waves 4-7 -> 0-3, then 2-3 -> 0-1).
// id bits: [2:0]=h (XCD slot), [7:3]=qb64, [8]=b, [9]=branch (global=0 first)
__global__ __launch_bounds__(512, 6) void attn8(const ushort_t* __restrict__ QKV,
                                                const ushort_t* __restrict__ VT,
                                                ushort_t* __restrict__ A2) {
    const int gid = blockIdx.x;
    const int h = gid & 7;
    const int qb = (gid >> 3) & 31;
    const int b = (gid >> 8) & 1;
    const bool LOCAL = gid >= 512;
    const int bh = b * 8 + h;
    const int coff = LOCAL ? 0 : 1536;
    const int aoff = LOCAL ? 0 : 512;

    const int tid = threadIdx.x, lane = tid & 63, w = tid >> 6;
    const int l31 = lane & 31, hi = lane >> 5;
    const int rg = w & 1, kg = w >> 1;

    __shared__ __align__(16) char pool[4 * 9216];   // stream: K 32x72 + V 64x36 ushort
    __shared__ float Mm[8][32];
    __shared__ float Ll[8][32];
    ushort_t* Kc = (ushort_t*)(pool + kg * 9216);
    ushort_t* Vc = (ushort_t*)(pool + kg * 9216 + 4608);

    const int qrow = qb * 64 + rg * 32 + l31;
    short8 qf[4];
    {
        const ushort_t* qp = QKV + (size_t)(b * 2048 + qrow) * 3072 + coff + h * 64 + hi * 8;
#pragma unroll
        for (int kd = 0; kd < 4; kd++) qf[kd] = *reinterpret_cast<const short8*>(qp + kd * 16);
    }

    f32x16 o0, o1;
#pragma unroll
    for (int i = 0; i < 16; i++) { o0[i] = 0.f; o1[i] = 0.f; }
    float mrow = -1e30f, lrow = 0.f;

    // kt indexes 32-row K/V tiles (64 total)
    int kt0 = 0, kt1 = 63;
    if (LOCAL) {
        kt0 = qb >= 2 ? 2 * qb - 4 : 0;
        kt1 = 2 * qb + 5 < 63 ? 2 * qb + 5 : 63;
    }
    const int NT = (kt1 - kt0 + 4) >> 2;   // ceil(n/4), uniform across WG

    // staging: 128 threads per kt-stream (waves 2kg, 2kg+1)
    const int t128 = tid & 127;
    const int kr0 = t128 >> 3, kc0 = (t128 & 7) * 8;   // K rows kr0, kr0+16
    const int vr0 = t128 >> 2, vc0 = (t128 & 3) * 8;   // V rows vr0, vr0+32
    const ushort_t* Kg = QKV + (size_t)(b * 2048) * 3072 + coff + 512 + h * 64;
    const ushort_t* Vg = VT + (size_t)(LOCAL ? 0 : 1) * 2097152 + (size_t)(bh * 64) * 2048;

    auto stage = [&](int kt) {
        const ushort_t* kp = Kg + (size_t)(kt * 32) * 3072;
        const ushort_t* vp = Vg + kt * 32;
        short8 k0v = *reinterpret_cast<const short8*>(kp + (size_t)kr0 * 3072 + kc0);
        short8 k1v = *reinterpret_cast<const short8*>(kp + (size_t)(kr0 + 16) * 3072 + kc0);
        short8 v0v = *reinterpret_cast<const short8*>(vp + (size_t)vr0 * 2048 + vc0);
        short8 v1v = *reinterpret_cast<const short8*>(vp + (size_t)(vr0 + 32) * 2048 + vc0);
        *reinterpret_cast<short8*>(&Kc[kr0 * 72 + kc0]) = k0v;
        *reinterpret_cast<short8*>(&Kc[(kr0 + 16) * 72 + kc0]) = k1v;
        *reinterpret_cast<short8*>(&Vc[vr0 * 36 + vc0]) = v0v;
        *reinterpret_cast<short8*>(&Vc[(vr0 + 32) * 36 + vc0]) = v1v;
    };

    auto tile_step = [&](int kt) {
        f32x16 s;
#pragma unroll
        for (int i = 0; i < 16; i++) s[i] = 0.f;
        __builtin_amdgcn_s_setprio(1);
#pragma unroll
        for (int kd = 0; kd < 4; kd++) {
            short8 kf = *reinterpret_cast<const short8*>(&Kc[l31 * 72 + kd * 16 + hi * 8]);
            s = MFMA32(kf, qf[kd], s, 0, 0, 0);
        }
        __builtin_amdgcn_s_setprio(0);
        if (LOCAL) {
#pragma unroll
            for (int r = 0; r < 16; r++) {
                int k0 = kt * 32 + (r & 3) + 8 * (r >> 2) + 4 * hi;
                int d0 = qrow - k0; d0 = d0 < 0 ? -d0 : d0;
                if (d0 > 128) s[r] = -2e30f;
            }
        }
        float pmax = -2e30f;
#pragma unroll
        for (int r = 0; r < 16; r++) pmax = fmaxf(pmax, s[r]);
        pmax = fmaxf(pmax, __shfl_xor(pmax, 32));
        if (!__all(pmax <= mrow + 8.f)) {
            float mnew = fmaxf(mrow, pmax);
            float sc = EXP2R(mrow - mnew);
            lrow *= sc;
#pragma unroll
            for (int r = 0; r < 16; r++) {
                int qo = (r & 3) + 8 * (r >> 2) + 4 * hi;
                float scv = __shfl(sc, qo);
                o0[r] *= scv; o1[r] *= scv;
            }
            mrow = mnew;
        }
        float ps = 0.f;
        uint32_t pk[8];
#pragma unroll
        for (int i = 0; i < 8; i++) {
            float a0 = EXP2R(s[2 * i] - mrow), b0 = EXP2R(s[2 * i + 1] - mrow);
            ps += a0 + b0;
            pk[i] = cvtpk(a0, b0);
        }
        ps += __shfl_xor(ps, 32);
        lrow += ps;

        __builtin_amdgcn_s_setprio(1);
#pragma unroll
        for (int m = 0; m < 2; m++) {
            uint32_t e0 = pk[4 * m + 0], e1 = pk[4 * m + 1];
            uint32_t e2 = pk[4 * m + 2], e3 = pk[4 * m + 3];
            auto w02 = __builtin_amdgcn_permlane32_swap(e0, e2, false, false);
            auto w13 = __builtin_amdgcn_permlane32_swap(e1, e3, false, false);
            u32x4 fv;
            fv[0] = w02[0]; fv[1] = w13[0]; fv[2] = w02[1]; fv[3] = w13[1];
            short8 pf = __builtin_bit_cast(short8, fv);
            short8 vf0 = *reinterpret_cast<const short8*>(&Vc[l31 * 36 + m * 16 + hi * 8]);
            short8 vf1 = *reinterpret_cast<const short8*>(&Vc[(32 + l31) * 36 + m * 16 + hi * 8]);
            o0 = MFMA32(pf, vf0, o0, 0, 0, 0);
            o1 = MFMA32(pf, vf1, o1, 0, 0, 0);
        }
        __builtin_amdgcn_s_setprio(0);
    };

    int kt = kt0 + kg;
    bool valid = (kt <= kt1);
    for (int i = 0; i < NT; i++) {
        if (valid) stage(kt);
        __syncthreads();                      // staging visible to both waves of stream
        if (valid) tile_step(kt);
        __syncthreads();                      // compute done before next overwrite
        kt += 4; valid = (kt <= kt1);
    }

    // ---- two-level register merge; Ob[4][32][68] f32 = 34816 B aliases pool ----
    float* Ob = (float*)pool;
    // level 1: waves 4-7 publish; waves 0-3 combine (kg pairs 0+2, 1+3, same rg)
    if (w >= 4) {
        const int slot = w - 4;
#pragma unroll
        for (int r = 0; r < 16; r++) {
            int qo = (r & 3) + 8 * (r >> 2) + 4 * hi;
            Ob[(slot * 32 + qo) * 68 + l31] = o0[r];
            Ob[(slot * 32 + qo) * 68 + 32 + l31] = o1[r];
        }
        if (lane < 32) { Mm[w][l31] = mrow; Ll[w][l31] = lrow; }
    }
    __syncthreads();
    if (w < 4) {
        float mb = Mm[w + 4][l31], lb = Ll[w + 4][l31];
        float M = fmaxf(mrow, mb);
        float ea = EXP2R(mrow - M), eb = EXP2R(mb - M);
        lrow = lrow * ea + lb * eb;
        mrow = M;
#pragma unroll
        for (int r = 0; r < 16; r++) {
            int qo = (r & 3) + 8 * (r >> 2) + 4 * hi;
            float sa = __shfl(ea, qo), sb = __shfl(eb, qo);
            o0[r] = o0[r] * sa + Ob[(w * 32 + qo) * 68 + l31] * sb;
            o1[r] = o1[r] * sa + Ob[(w * 32 + qo) * 68 + 32 + l31] * sb;
        }
    }
    __syncthreads();
    // level 2: waves 2-3 publish; waves 0-1 combine (kg pairs 0+1, same rg) + write
    if (w >= 2 && w < 4) {
        const int slot = w - 2;
#pragma unroll
        for (int r = 0; r < 16; r++) {
            int qo = (r & 3) + 8 * (r >> 2) + 4 * hi;
            Ob[(slot * 32 + qo) * 68 + l31] = o0[r];
            Ob[(slot * 32 + qo) * 68 + 32 + l31] = o1[r];
        }
        if (lane < 32) { Mm[w][l31] = mrow; Ll[w][l31] = lrow; }
    }
    __syncthreads();
    if (w < 2) {
        float mb = Mm[w + 2][l31], lb = Ll[w + 2][l31];
        float M = fmaxf(mrow, mb);
        float ea = EXP2R(mrow - M), eb = EXP2R(mb - M);
        float lfin = lrow * ea + lb * eb;
        float inv = 1.0f / lfin;
#pragma unroll
        for (int r = 0; r < 16; r++) {
            int qo = (r & 3) + 8 * (r >> 2) + 4 * hi;
            float sa = __shfl(ea, qo), sb = __shfl(eb, qo);
            float iv = __shfl(inv, qo);
            float v0 = o0[r] * sa + Ob[(w * 32 + qo) * 68 + l31] * sb;
            float v1 = o1[r] * sa + Ob[(w * 32 + qo) * 68 + 32 + l31] * sb;
            size_t rowb = (size_t)(b * 2048 + qb * 64 + w * 32 + qo) * 1024 + aoff + h * 64;
            A2[rowb + l31] = f2bf(v0 * iv);
            A2[rowb + 32 + l31] = f2bf(v1 * iv);
        }
    }
}

// ---------------- launcher ----------------
extern "C" void kernel_launch(void* const* d_in, const int* in_sizes, int n_in,
                              void* d_out, int out_size, void* d_ws, size_t ws_size,
                              hipStream_t stream) {
    const float* x      = (const float*)d_in[0];
    const float* wl_in  = (const float*)d_in[2];
    const float* bl_in  = (const float*)d_in[3];
    const float* wl_out = (const float*)d_in[4];
    const float* bl_out = (const float*)d_in[5];
    const float* wg_in  = (const float*)d_in[6];
    const float* bg_in  = (const float*)d_in[7];
    const float* wg_out = (const float*)d_in[8];
    const float* bg_out = (const float*)d_in[9];
    const float* gate   = (const float*)d_in[10];

    char* ws = (char*)d_ws;
    ushort_t* xb   = (ushort_t*)ws;  ws += (size_t)4096 * 512 * 2;
    ushort_t* Wqkv = (ushort_t*)ws;  ws += (size_t)3072 * 512 * 2;
    float*    bqkv = (float*)ws;     ws += (size_t)3072 * 4;
    ushort_t* QKV  = (ushort_t*)ws;  ws += (size_t)4096 * 3072 * 2;
    ushort_t* VT   = (ushort_t*)ws;  ws += (size_t)2 * 16 * 64 * 2048 * 2;
    ushort_t* A2   = (ushort_t*)ws;  ws += (size_t)4096 * 1024 * 2;
    ushort_t* W3   = (ushort_t*)ws;  ws += (size_t)512 * 1024 * 2;
    float*    b3   = (float*)ws;     ws += (size_t)512 * 4;

    prep_all<<<2048, 256, 0, stream>>>(x, wl_in, wg_in, bl_in, bg_in,
                                       wl_out, wg_out, bl_out, bg_out, gate,
                                       xb, Wqkv, bqkv, W3, b3);

    gemm_bt<4, true, true><<<dim3(32, 24), 256, 0, stream>>>(xb, Wqkv, bqkv, QKV, VT,
                                                             4096, 3072, 512);
    attn8<<<1024, 512, 0, stream>>>(QKV, VT, A2);
    gemm_bt<1, false, false><<<dim3(32, 16), 256, 0, stream>>>(A2, W3, b3, d_out, nullptr,
                                                               4096, 512, 1024);
}

// Round 14
// 101.817 us; speedup vs baseline: 1.5191x; 1.5191x over previous
//
#include <hip/hip_runtime.h>
#include <stdint.h>

typedef unsigned short ushort_t;
typedef __attribute__((ext_vector_type(8))) short short8;
typedef __attribute__((ext_vector_type(4))) float f32x4;
typedef __attribute__((ext_vector_type(16))) float f32x16;
typedef __attribute__((ext_vector_type(4))) uint32_t u32x4;
typedef __attribute__((ext_vector_type(2))) uint32_t u32x2;

#define MFMA16 __builtin_amdgcn_mfma_f32_16x16x32_bf16
#define MFMA32 __builtin_amdgcn_mfma_f32_32x32x16_bf16

// global->LDS direct (16B/lane); dest = wave-uniform base + lane*16 (m97/m104)
#define GLOAD_LDS16(gp, lp)                                                  \
    __builtin_amdgcn_global_load_lds(                                        \
        (const __attribute__((address_space(1))) void*)(gp),                 \
        (__attribute__((address_space(3))) void*)(lp), 16, 0, 0)

__device__ inline ushort_t f2bf(float f) {
    union { float f; uint32_t u; } x; x.f = f;
    uint32_t r = x.u + 0x7FFFu + ((x.u >> 16) & 1u);
    return (ushort_t)(r >> 16);
}
// single-instruction packed f32->bf16 (RNE), gfx950
__device__ inline uint32_t cvtpk(float lo, float hi) {
    uint32_t r;
    asm("v_cvt_pk_bf16_f32 %0, %1, %2" : "=v"(r) : "v"(lo), "v"(hi));
    return r;
}
#define EXP2R __builtin_amdgcn_exp2f   // raw v_exp_f32

// ---------------- fused prep: conv_x + prep_wqkv + prep_w3 ----------------
__global__ __launch_bounds__(256) void prep_all(const float* __restrict__ x,
                                                const float* __restrict__ wl_in,
                                                const float* __restrict__ wg_in,
                                                const float* __restrict__ bl_in,
                                                const float* __restrict__ bg_in,
                                                const float* __restrict__ wl_out,
                                                const float* __restrict__ wg_out,
                                                const float* __restrict__ bl_out,
                                                const float* __restrict__ bg_out,
                                                const float* __restrict__ gate,
                                                ushort_t* __restrict__ xb,
                                                ushort_t* __restrict__ Wqkv,
                                                float* __restrict__ bqkv,
                                                ushort_t* __restrict__ W3,
                                                float* __restrict__ b3) {
    const float QSC = 0.125f * 1.44269504089f;   // fold score-scale * log2(e) into Q
    int gid = blockIdx.x * 256 + threadIdx.x;
    if (gid < 262144) {                       // x -> bf16 (4096*512/8)
        int base = gid * 8;
        short8 v;
#pragma unroll
        for (int j = 0; j < 8; j++) v[j] = (short)f2bf(x[base + j]);
        *reinterpret_cast<short8*>(&xb[base]) = v;
    } else if (gid < 458752) {                // Wqkv (3072*512/8)
        int g2 = gid - 262144;
        int base = g2 * 8;
        short8 v;
#pragma unroll
        for (int j = 0; j < 8; j++) {
            int e = base + j;
            int n = e >> 9;
            int nm = n >= 1536 ? n - 1536 : n;
            float sc = (nm < 512) ? QSC : 1.0f;
            float f = (e < 1536 * 512) ? wl_in[e] : wg_in[e - 1536 * 512];
            v[j] = (short)f2bf(f * sc);
        }
        *reinterpret_cast<short8*>(&Wqkv[base]) = v;
        if (g2 < 3072) {
            int nm = g2 >= 1536 ? g2 - 1536 : g2;
            float sc = (nm < 512) ? QSC : 1.0f;
            bqkv[g2] = ((g2 < 1536) ? bl_in[g2] : bg_in[g2 - 1536]) * sc;
        }
    } else {                                  // W3 (512*1024/8)
        int g2 = gid - 458752;
        float gv = gate[0];
        int base = g2 * 8;
        short8 v;
#pragma unroll
        for (int j = 0; j < 8; j++) {
            int e = base + j;
            int n = e >> 10, k = e & 1023;
            float f = (k < 512) ? gv * wl_out[n * 512 + k]
                                : (1.0f - gv) * wg_out[n * 512 + (k - 512)];
            v[j] = (short)f2bf(f);
        }
        *reinterpret_cast<short8*>(&W3[base]) = v;
        if (g2 < 512) b3[g2] = gv * bl_out[g2] + (1.0f - gv) * bg_out[g2];
    }
}

// ---------------- GEMM: C[M][N] = A[M][K] * B[N][K]^T + bias ----------------
// m97 staging (global_load_lds x16B, linear LDS) + T1 XCD-chunked 1D grid.
// Requires M == 4096 (bm = swz & 31). nwg must be divisible by 8.
// FUSE_VT: V-range columns (n in [1024,1536)+[2560,3072)) go to VT[br][dfull][l].
template<int NI, bool OUT_BF16, bool FUSE_VT>
__global__ __launch_bounds__(256) void gemm_bt(const ushort_t* __restrict__ A,
                                               const ushort_t* __restrict__ B,
                                               const float* __restrict__ bias,
                                               void* __restrict__ Cout,
                                               ushort_t* __restrict__ VTout,
                                               int M, int N, int K) {
    constexpr int TN = NI * 32;
    __shared__ __align__(16) ushort_t As[128 * 64];
    __shared__ __align__(16) ushort_t Bs[TN * 64];
    const int tid = threadIdx.x;
    const int lane = tid & 63, wid = tid >> 6;
    const int g = lane >> 4, c = lane & 15;
    const int wm = wid >> 1, wn = wid & 1;
    // XCD-chunked swizzle (T1): XCD k executes originals [k*q, (k+1)*q)
    const int nwg = gridDim.x, q = nwg >> 3, id = blockIdx.x;
    const int swz = (id & 7) * q + (id >> 3);
    const int bm = swz & 31;          // M/128 == 32
    const int bn = swz >> 5;

    f32x4 acc[4][NI];
#pragma unroll
    for (int i = 0; i < 4; i++)
#pragma unroll
        for (int j = 0; j < NI; j++) acc[i][j] = f32x4{0.f, 0.f, 0.f, 0.f};

    for (int ks = 0; ks < K; ks += 64) {
#pragma unroll
        for (int it = 0; it < 4; it++) {           // A: 128x64 = 1024 chunks
            int idx = it * 256 + tid;
            int r = idx >> 3, ch = idx & 7;
            GLOAD_LDS16(&A[(size_t)(bm * 128 + r) * K + ks + ch * 8],
                        &As[(size_t)(idx & ~63) * 8]);
        }
#pragma unroll
        for (int it = 0; it < TN / 32; it++) {     // B: TN x 64
            int idx = it * 256 + tid;
            int r = idx >> 3, ch = idx & 7;
            GLOAD_LDS16(&B[(size_t)(bn * TN + r) * K + ks + ch * 8],
                        &Bs[(size_t)(idx & ~63) * 8]);
        }
        __syncthreads();                           // drains vmcnt (compiler)
#pragma unroll
        for (int kk = 0; kk < 2; kk++) {
            short8 a[4], b[NI];
#pragma unroll
            for (int mi = 0; mi < 4; mi++)
                a[mi] = *reinterpret_cast<const short8*>(&As[(wm * 64 + mi * 16 + c) * 64 + kk * 32 + g * 8]);
#pragma unroll
            for (int ni = 0; ni < NI; ni++)
                b[ni] = *reinterpret_cast<const short8*>(&Bs[(wn * (NI * 16) + ni * 16 + c) * 64 + kk * 32 + g * 8]);
#pragma unroll
            for (int mi = 0; mi < 4; mi++)
#pragma unroll
                for (int ni = 0; ni < NI; ni++)
                    acc[mi][ni] = MFMA16(a[mi], b[ni], acc[mi][ni], 0, 0, 0);
        }
        __syncthreads();
    }
#pragma unroll
    for (int mi = 0; mi < 4; mi++) {
#pragma unroll
        for (int ni = 0; ni < NI; ni++) {
            int n = bn * TN + wn * (NI * 16) + ni * 16 + c;
            float bv = bias[n];
            float v0 = acc[mi][ni][0] + bv;
            float v1 = acc[mi][ni][1] + bv;
            float v2 = acc[mi][ni][2] + bv;
            float v3 = acc[mi][ni][3] + bv;
            int m0 = bm * 128 + wm * 64 + mi * 16 + g * 4;
            bool isV = FUSE_VT && (n >= 1024) && (n < 1536 || n >= 2560);
            if (isV) {
                int br = n >= 1536 ? 1 : 0;
                int dfull = (br ? n - 1536 : n) - 1024;        // 0..511
                int bb = m0 >> 11, l0 = m0 & 2047;
                u32x2 pk;
                pk[0] = cvtpk(v0, v1);
                pk[1] = cvtpk(v2, v3);
                *reinterpret_cast<u32x2*>(
                    &VTout[(size_t)br * 2097152 + ((size_t)bb * 512 + dfull) * 2048 + l0]) = pk;
            } else {
                float vv[4] = {v0, v1, v2, v3};
#pragma unroll
                for (int r = 0; r < 4; r++) {
                    int m = m0 + r;
                    if (OUT_BF16) ((ushort_t*)Cout)[(size_t)m * N + n] = f2bf(vv[r]);
                    else          ((float*)Cout)[(size_t)m * N + n] = vv[r];
                }
            }
        }
    }
}

// ---------------- attention: 8 waves, 64 q-rows, 4-way kt-split, LDS merge ----------------
// r12-proven version (45.5us): 72-pad LDS, reg-staged stage(), 2 barriers/iter,
// launch_bounds(512,2) -> VGPR 64, 2 WGs/CU; TLP hides staging latency.
// (r7/r13: forcing more blocks spills; r9: prefetch ILP loses to TLP; r11: gload banks.)
// id bits: [2:0]=h (XCD slot), [7:3]=qb64, [8]=b, [9]=branch (global=0 first)
__global__ __launch_bounds__(512, 2) void attn8(const ushort_t* __restrict__ QKV,
                                                const ushort_t* __restrict__ VT,
                                                ushort_t* __restrict__ A2) {
    const int gid = blockIdx.x;
    const int h = gid & 7;
    const int qb = (gid >> 3) & 31;
    const int b = (gid >> 8) & 1;
    const bool LOCAL = gid >= 512;
    const int bh = b * 8 + h;
    const int coff = LOCAL ? 0 : 1536;
    const int aoff = LOCAL ? 0 : 512;

    const int tid = threadIdx.x, lane = tid & 63, w = tid >> 6;
    const int l31 = lane & 31, hi = lane >> 5;
    const int rg = w & 1, kg = w >> 1;

    __shared__ __align__(16) char pool[4 * 2 * 9216];   // 4 streams x (K,V) 64x72 ushort
    __shared__ float Mm[8][32];
    __shared__ float Ll[8][32];
    ushort_t* Kc = (ushort_t*)(pool + kg * 18432);
    ushort_t* Vc = (ushort_t*)(pool + kg * 18432 + 9216);

    const int qrow = qb * 64 + rg * 32 + l31;
    short8 qf[4];
    {
        const ushort_t* qp = QKV + (size_t)(b * 2048 + qrow) * 3072 + coff + h * 64 + hi * 8;
#pragma unroll
        for (int kd = 0; kd < 4; kd++) qf[kd] = *reinterpret_cast<const short8*>(qp + kd * 16);
    }

    f32x16 o0, o1;
#pragma unroll
    for (int i = 0; i < 16; i++) { o0[i] = 0.f; o1[i] = 0.f; }
    float mrow = -1e30f, lrow = 0.f;

    int kt0 = 0, kt1 = 31;
    if (LOCAL) {
        kt0 = qb >= 2 ? qb - 2 : 0;
        kt1 = qb + 2 < 31 ? qb + 2 : 31;
    }
    const int NT = (kt1 - kt0 + 4) >> 2;   // ceil(n/4), uniform across WG

    // staging: 128 threads per kt-stream (waves 2kg, 2kg+1)
    const int t128 = tid & 127;
    const int r0 = t128 >> 3, c0 = (t128 & 7) * 8;   // rows r0+16j, 16B chunk c0
    const ushort_t* Kg = QKV + (size_t)(b * 2048) * 3072 + coff + 512 + h * 64;
    const ushort_t* Vg = VT + (size_t)(LOCAL ? 0 : 1) * 2097152 + (size_t)(bh * 64) * 2048;

    auto stage = [&](int kt) {
        const ushort_t* kp = Kg + (size_t)(kt * 64) * 3072;
        const ushort_t* vp = Vg + kt * 64;
        short8 kl[4], vl[4];
#pragma unroll
        for (int j = 0; j < 4; j++) {
            kl[j] = *reinterpret_cast<const short8*>(kp + (size_t)(r0 + 16 * j) * 3072 + c0);
            vl[j] = *reinterpret_cast<const short8*>(vp + (size_t)(r0 + 16 * j) * 2048 + c0);
        }
#pragma unroll
        for (int j = 0; j < 4; j++) {
            *reinterpret_cast<short8*>(&Kc[(r0 + 16 * j) * 72 + c0]) = kl[j];
            *reinterpret_cast<short8*>(&Vc[(r0 + 16 * j) * 72 + c0]) = vl[j];
        }
    };

    auto tile_step = [&](int kt) {
        f32x16 s0, s1;
#pragma unroll
        for (int i = 0; i < 16; i++) { s0[i] = 0.f; s1[i] = 0.f; }
        __builtin_amdgcn_s_setprio(1);
#pragma unroll
        for (int kd = 0; kd < 4; kd++) {
            short8 kf0 = *reinterpret_cast<const short8*>(&Kc[l31 * 72 + kd * 16 + hi * 8]);
            short8 kf1 = *reinterpret_cast<const short8*>(&Kc[(32 + l31) * 72 + kd * 16 + hi * 8]);
            s0 = MFMA32(kf0, qf[kd], s0, 0, 0, 0);
            s1 = MFMA32(kf1, qf[kd], s1, 0, 0, 0);
        }
        __builtin_amdgcn_s_setprio(0);
        if (LOCAL) {
#pragma unroll
            for (int r = 0; r < 16; r++) {
                int k0 = kt * 64 + (r & 3) + 8 * (r >> 2) + 4 * hi;
                int d0 = qrow - k0; d0 = d0 < 0 ? -d0 : d0;
                int d1 = qrow - (k0 + 32); d1 = d1 < 0 ? -d1 : d1;
                if (d0 > 128) s0[r] = -2e30f;
                if (d1 > 128) s1[r] = -2e30f;
            }
        }
        float pmax = -2e30f;
#pragma unroll
        for (int r = 0; r < 16; r++) pmax = fmaxf(pmax, fmaxf(s0[r], s1[r]));
        pmax = fmaxf(pmax, __shfl_xor(pmax, 32));
        if (!__all(pmax <= mrow + 8.f)) {
            float mnew = fmaxf(mrow, pmax);
            float sc = EXP2R(mrow - mnew);
            lrow *= sc;
#pragma unroll
            for (int r = 0; r < 16; r++) {
                int qo = (r & 3) + 8 * (r >> 2) + 4 * hi;
                float scv = __shfl(sc, qo);
                o0[r] *= scv; o1[r] *= scv;
            }
            mrow = mnew;
        }
        float ps0 = 0.f, ps1 = 0.f;
        uint32_t pk0[8], pk1[8];
#pragma unroll
        for (int i = 0; i < 8; i++) {
            float a0 = EXP2R(s0[2 * i] - mrow), b0 = EXP2R(s0[2 * i + 1] - mrow);
            float a1 = EXP2R(s1[2 * i] - mrow), b1 = EXP2R(s1[2 * i + 1] - mrow);
            ps0 += a0 + b0; ps1 += a1 + b1;
            pk0[i] = cvtpk(a0, b0);
            pk1[i] = cvtpk(a1, b1);
        }
        float psum = ps0 + ps1;
        psum += __shfl_xor(psum, 32);
        lrow += psum;

        __builtin_amdgcn_s_setprio(1);
#pragma unroll
        for (int kb = 0; kb < 2; kb++) {
#pragma unroll
            for (int m = 0; m < 2; m++) {
                uint32_t e0 = kb ? pk1[4 * m + 0] : pk0[4 * m + 0];
                uint32_t e1 = kb ? pk1[4 * m + 1] : pk0[4 * m + 1];
                uint32_t e2 = kb ? pk1[4 * m + 2] : pk0[4 * m + 2];
                uint32_t e3 = kb ? pk1[4 * m + 3] : pk0[4 * m + 3];
                auto w02 = __builtin_amdgcn_permlane32_swap(e0, e2, false, false);
                auto w13 = __builtin_amdgcn_permlane32_swap(e1, e3, false, false);
                u32x4 fv;
                fv[0] = w02[0]; fv[1] = w13[0]; fv[2] = w02[1]; fv[3] = w13[1];
                short8 pf = __builtin_bit_cast(short8, fv);
                int km = kb * 2 + m;
                short8 vf0 = *reinterpret_cast<const short8*>(&Vc[l31 * 72 + km * 16 + hi * 8]);
                short8 vf1 = *reinterpret_cast<const short8*>(&Vc[(32 + l31) * 72 + km * 16 + hi * 8]);
                o0 = MFMA32(pf, vf0, o0, 0, 0, 0);
                o1 = MFMA32(pf, vf1, o1, 0, 0, 0);
            }
        }
        __builtin_amdgcn_s_setprio(0);
    };

    int kt = kt0 + kg;
    bool valid = (kt <= kt1);
    for (int i = 0; i < NT; i++) {
        if (valid) stage(kt);
        __syncthreads();                      // staging visible to both waves of stream
        if (valid) tile_step(kt);
        __syncthreads();                      // compute done before next overwrite
        kt += 4; valid = (kt <= kt1);
    }

    // ---- merge: Ob aliases pool (safe after final barrier) ----
    float* Ob = (float*)pool;                 // [8][32][68] = 69632 B <= 73728
#pragma unroll
    for (int r = 0; r < 16; r++) {
        int qo = (r & 3) + 8 * (r >> 2) + 4 * hi;
        Ob[(w * 32 + qo) * 68 + l31] = o0[r];
        Ob[(w * 32 + qo) * 68 + 32 + l31] = o1[r];
    }
    if (lane < 32) { Mm[w][l31] = mrow; Ll[w][l31] = lrow; }
    __syncthreads();

    {
        const int row = w * 8 + (lane >> 3);  // 0..63
        const int cg = lane & 7;
        const int rg2 = row >> 5, r32 = row & 31;
        float m[4], e[4];
#pragma unroll
        for (int p = 0; p < 4; p++) m[p] = Mm[rg2 + 2 * p][r32];
        float M = fmaxf(fmaxf(m[0], m[1]), fmaxf(m[2], m[3]));
        float L = 0.f;
#pragma unroll
        for (int p = 0; p < 4; p++) {
            e[p] = EXP2R(m[p] - M);
            L += Ll[rg2 + 2 * p][r32] * e[p];
        }
        float inv = 1.0f / L;
        f32x4 accA = f32x4{0.f, 0.f, 0.f, 0.f}, accB = f32x4{0.f, 0.f, 0.f, 0.f};
#pragma unroll
        for (int p = 0; p < 4; p++) {
            int slot = rg2 + 2 * p;
            accA += *reinterpret_cast<const f32x4*>(&Ob[(slot * 32 + r32) * 68 + cg * 8]) * e[p];
            accB += *reinterpret_cast<const f32x4*>(&Ob[(slot * 32 + r32) * 68 + cg * 8 + 4]) * e[p];
        }
        u32x4 fv;
        fv[0] = cvtpk(accA[0] * inv, accA[1] * inv);
        fv[1] = cvtpk(accA[2] * inv, accA[3] * inv);
        fv[2] = cvtpk(accB[0] * inv, accB[1] * inv);
        fv[3] = cvtpk(accB[2] * inv, accB[3] * inv);
        *reinterpret_cast<u32x4*>(&A2[(size_t)(b * 2048 + qb * 64 + row) * 1024 + aoff + h * 64 + cg * 8]) = fv;
    }
}

// ---------------- launcher ----------------
extern "C" void kernel_launch(void* const* d_in, const int* in_sizes, int n_in,
                              void* d_out, int out_size, void* d_ws, size_t ws_size,
                              hipStream_t stream) {
    const float* x      = (const float*)d_in[0];
    const float* wl_in  = (const float*)d_in[2];
    const float* bl_in  = (const float*)d_in[3];
    const float* wl_out = (const float*)d_in[4];
    const float* bl_out = (const float*)d_in[5];
    const float* wg_in  = (const float*)d_in[6];
    const float* bg_in  = (const float*)d_in[7];
    const float* wg_out = (const float*)d_in[8];
    const float* bg_out = (const float*)d_in[9];
    const float* gate   = (const float*)d_in[10];

    char* ws = (char*)d_ws;
    ushort_t* xb   = (ushort_t*)ws;  ws += (size_t)4096 * 512 * 2;
    ushort_t* Wqkv = (ushort_t*)ws;  ws += (size_t)3072 * 512 * 2;
    float*    bqkv = (float*)ws;     ws += (size_t)3072 * 4;
    ushort_t* QKV  = (ushort_t*)ws;  ws += (size_t)4096 * 3072 * 2;
    ushort_t* VT   = (ushort_t*)ws;  ws += (size_t)2 * 16 * 64 * 2048 * 2;
    ushort_t* A2   = (ushort_t*)ws;  ws += (size_t)4096 * 1024 * 2;
    ushort_t* W3   = (ushort_t*)ws;  ws += (size_t)512 * 1024 * 2;
    float*    b3   = (float*)ws;     ws += (size_t)512 * 4;

    prep_all<<<2048, 256, 0, stream>>>(x, wl_in, wg_in, bl_in, bg_in,
                                       wl_out, wg_out, bl_out, bg_out, gate,
                                       xb, Wqkv, bqkv, W3, b3);

    gemm_bt<4, true, true><<<768, 256, 0, stream>>>(xb, Wqkv, bqkv, QKV, VT,
                                                    4096, 3072, 512);
    attn8<<<1024, 512, 0, stream>>>(QKV, VT, A2);
    gemm_bt<1, false, false><<<512, 256, 0, stream>>>(A2, W3, b3, d_out, nullptr,
                                                      4096, 512, 1024);
}

// Round 15
// 97.413 us; speedup vs baseline: 1.5877x; 1.0452x over previous
//
#include <hip/hip_runtime.h>
#include <stdint.h>

typedef unsigned short ushort_t;
typedef __attribute__((ext_vector_type(8))) short short8;
typedef __attribute__((ext_vector_type(4))) float f32x4;
typedef __attribute__((ext_vector_type(16))) float f32x16;
typedef __attribute__((ext_vector_type(4))) uint32_t u32x4;
typedef __attribute__((ext_vector_type(2))) uint32_t u32x2;

#define MFMA16 __builtin_amdgcn_mfma_f32_16x16x32_bf16
#define MFMA32 __builtin_amdgcn_mfma_f32_32x32x16_bf16

// global->LDS direct (16B/lane); dest = wave-uniform base + lane*16 (m97/m104)
#define GLOAD_LDS16(gp, lp)                                                  \
    __builtin_amdgcn_global_load_lds(                                        \
        (const __attribute__((address_space(1))) void*)(gp),                 \
        (__attribute__((address_space(3))) void*)(lp), 16, 0, 0)

__device__ inline ushort_t f2bf(float f) {
    union { float f; uint32_t u; } x; x.f = f;
    uint32_t r = x.u + 0x7FFFu + ((x.u >> 16) & 1u);
    return (ushort_t)(r >> 16);
}
// single-instruction packed f32->bf16 (RNE), gfx950
__device__ inline uint32_t cvtpk(float lo, float hi) {
    uint32_t r;
    asm("v_cvt_pk_bf16_f32 %0, %1, %2" : "=v"(r) : "v"(lo), "v"(hi));
    return r;
}
#define EXP2R __builtin_amdgcn_exp2f   // raw v_exp_f32

// ---------------- fused prep: conv_x + prep_wqkv + prep_w3 ----------------
__global__ __launch_bounds__(256) void prep_all(const float* __restrict__ x,
                                                const float* __restrict__ wl_in,
                                                const float* __restrict__ wg_in,
                                                const float* __restrict__ bl_in,
                                                const float* __restrict__ bg_in,
                                                const float* __restrict__ wl_out,
                                                const float* __restrict__ wg_out,
                                                const float* __restrict__ bl_out,
                                                const float* __restrict__ bg_out,
                                                const float* __restrict__ gate,
                                                ushort_t* __restrict__ xb,
                                                ushort_t* __restrict__ Wqkv,
                                                float* __restrict__ bqkv,
                                                ushort_t* __restrict__ W3,
                                                float* __restrict__ b3) {
    const float QSC = 0.125f * 1.44269504089f;   // fold score-scale * log2(e) into Q
    int gid = blockIdx.x * 256 + threadIdx.x;
    if (gid < 262144) {                       // x -> bf16 (4096*512/8)
        int base = gid * 8;
        short8 v;
#pragma unroll
        for (int j = 0; j < 8; j++) v[j] = (short)f2bf(x[base + j]);
        *reinterpret_cast<short8*>(&xb[base]) = v;
    } else if (gid < 458752) {                // Wqkv (3072*512/8)
        int g2 = gid - 262144;
        int base = g2 * 8;
        short8 v;
#pragma unroll
        for (int j = 0; j < 8; j++) {
            int e = base + j;
            int n = e >> 9;
            int nm = n >= 1536 ? n - 1536 : n;
            float sc = (nm < 512) ? QSC : 1.0f;
            float f = (e < 1536 * 512) ? wl_in[e] : wg_in[e - 1536 * 512];
            v[j] = (short)f2bf(f * sc);
        }
        *reinterpret_cast<short8*>(&Wqkv[base]) = v;
        if (g2 < 3072) {
            int nm = g2 >= 1536 ? g2 - 1536 : g2;
            float sc = (nm < 512) ? QSC : 1.0f;
            bqkv[g2] = ((g2 < 1536) ? bl_in[g2] : bg_in[g2 - 1536]) * sc;
        }
    } else {                                  // W3 (512*1024/8)
        int g2 = gid - 458752;
        float gv = gate[0];
        int base = g2 * 8;
        short8 v;
#pragma unroll
        for (int j = 0; j < 8; j++) {
            int e = base + j;
            int n = e >> 10, k = e & 1023;
            float f = (k < 512) ? gv * wl_out[n * 512 + k]
                                : (1.0f - gv) * wg_out[n * 512 + (k - 512)];
            v[j] = (short)f2bf(f);
        }
        *reinterpret_cast<short8*>(&W3[base]) = v;
        if (g2 < 512) b3[g2] = gv * bl_out[g2] + (1.0f - gv) * bg_out[g2];
    }
}

// ---------------- GEMM: C[M][N] = A[M][K] * B[N][K]^T + bias ----------------
// m97 staging (global_load_lds x16B, linear LDS), 2-D grid (x=bm fastest):
// default round-robin XCD assignment -> XCD = bm%8 -> per-XCD A-stripe affinity
// (0.5MB L2-resident). Do NOT remap blockIdx (r14: chunked swizzle cost +6us).
// FUSE_VT: V-range columns (n in [1024,1536)+[2560,3072)) go to VT[br][dfull][l].
template<int NI, bool OUT_BF16, bool FUSE_VT>
__global__ __launch_bounds__(256) void gemm_bt(const ushort_t* __restrict__ A,
                                               const ushort_t* __restrict__ B,
                                               const float* __restrict__ bias,
                                               void* __restrict__ Cout,
                                               ushort_t* __restrict__ VTout,
                                               int M, int N, int K) {
    constexpr int TN = NI * 32;
    __shared__ __align__(16) ushort_t As[128 * 64];
    __shared__ __align__(16) ushort_t Bs[TN * 64];
    const int tid = threadIdx.x;
    const int lane = tid & 63, wid = tid >> 6;
    const int g = lane >> 4, c = lane & 15;
    const int wm = wid >> 1, wn = wid & 1;
    const int bm = blockIdx.x, bn = blockIdx.y;

    f32x4 acc[4][NI];
#pragma unroll
    for (int i = 0; i < 4; i++)
#pragma unroll
        for (int j = 0; j < NI; j++) acc[i][j] = f32x4{0.f, 0.f, 0.f, 0.f};

    for (int ks = 0; ks < K; ks += 64) {
#pragma unroll
        for (int it = 0; it < 4; it++) {           // A: 128x64 = 1024 chunks
            int idx = it * 256 + tid;
            int r = idx >> 3, ch = idx & 7;
            GLOAD_LDS16(&A[(size_t)(bm * 128 + r) * K + ks + ch * 8],
                        &As[(size_t)(idx & ~63) * 8]);
        }
#pragma unroll
        for (int it = 0; it < TN / 32; it++) {     // B: TN x 64
            int idx = it * 256 + tid;
            int r = idx >> 3, ch = idx & 7;
            GLOAD_LDS16(&B[(size_t)(bn * TN + r) * K + ks + ch * 8],
                        &Bs[(size_t)(idx & ~63) * 8]);
        }
        __syncthreads();                           // drains vmcnt (compiler)
#pragma unroll
        for (int kk = 0; kk < 2; kk++) {
            short8 a[4], b[NI];
#pragma unroll
            for (int mi = 0; mi < 4; mi++)
                a[mi] = *reinterpret_cast<const short8*>(&As[(wm * 64 + mi * 16 + c) * 64 + kk * 32 + g * 8]);
#pragma unroll
            for (int ni = 0; ni < NI; ni++)
                b[ni] = *reinterpret_cast<const short8*>(&Bs[(wn * (NI * 16) + ni * 16 + c) * 64 + kk * 32 + g * 8]);
#pragma unroll
            for (int mi = 0; mi < 4; mi++)
#pragma unroll
                for (int ni = 0; ni < NI; ni++)
                    acc[mi][ni] = MFMA16(a[mi], b[ni], acc[mi][ni], 0, 0, 0);
        }
        __syncthreads();
    }
#pragma unroll
    for (int mi = 0; mi < 4; mi++) {
#pragma unroll
        for (int ni = 0; ni < NI; ni++) {
            int n = bn * TN + wn * (NI * 16) + ni * 16 + c;
            float bv = bias[n];
            float v0 = acc[mi][ni][0] + bv;
            float v1 = acc[mi][ni][1] + bv;
            float v2 = acc[mi][ni][2] + bv;
            float v3 = acc[mi][ni][3] + bv;
            int m0 = bm * 128 + wm * 64 + mi * 16 + g * 4;
            bool isV = FUSE_VT && (n >= 1024) && (n < 1536 || n >= 2560);
            if (isV) {
                int br = n >= 1536 ? 1 : 0;
                int dfull = (br ? n - 1536 : n) - 1024;        // 0..511
                int bb = m0 >> 11, l0 = m0 & 2047;
                u32x2 pk;
                pk[0] = cvtpk(v0, v1);
                pk[1] = cvtpk(v2, v3);
                *reinterpret_cast<u32x2*>(
                    &VTout[(size_t)br * 2097152 + ((size_t)bb * 512 + dfull) * 2048 + l0]) = pk;
            } else {
                float vv[4] = {v0, v1, v2, v3};
#pragma unroll
                for (int r = 0; r < 4; r++) {
                    int m = m0 + r;
                    if (OUT_BF16) ((ushort_t*)Cout)[(size_t)m * N + n] = f2bf(vv[r]);
                    else          ((float*)Cout)[(size_t)m * N + n] = vv[r];
                }
            }
        }
    }
}

// ---------------- attention: 8 waves, 64 q-rows, 4-way kt-split, LDS merge ----------------
// r12-proven version (43.5-45.5us): 72-pad LDS, reg-staged stage(), 2 barriers/iter,
// launch_bounds(512,2) -> VGPR 64, 2 WGs/CU; TLP hides staging latency.
// (r7/r13: forcing more blocks spills; r9: prefetch ILP loses to TLP; r11: gload banks.)
// id bits: [2:0]=h (XCD slot), [7:3]=qb64, [8]=b, [9]=branch (global=0 first)
__global__ __launch_bounds__(512, 2) void attn8(const ushort_t* __restrict__ QKV,
                                                const ushort_t* __restrict__ VT,
                                                ushort_t* __restrict__ A2) {
    const int gid = blockIdx.x;
    const int h = gid & 7;
    const int qb = (gid >> 3) & 31;
    const int b = (gid >> 8) & 1;
    const bool LOCAL = gid >= 512;
    const int bh = b * 8 + h;
    const int coff = LOCAL ? 0 : 1536;
    const int aoff = LOCAL ? 0 : 512;

    const int tid = threadIdx.x, lane = tid & 63, w = tid >> 6;
    const int l31 = lane & 31, hi = lane >> 5;
    const int rg = w & 1, kg = w >> 1;

    __shared__ __align__(16) char pool[4 * 2 * 9216];   // 4 streams x (K,V) 64x72 ushort
    __shared__ float Mm[8][32];
    __shared__ float Ll[8][32];
    ushort_t* Kc = (ushort_t*)(pool + kg * 18432);
    ushort_t* Vc = (ushort_t*)(pool + kg * 18432 + 9216);

    const int qrow = qb * 64 + rg * 32 + l31;
    short8 qf[4];
    {
        const ushort_t* qp = QKV + (size_t)(b * 2048 + qrow) * 3072 + coff + h * 64 + hi * 8;
#pragma unroll
        for (int kd = 0; kd < 4; kd++) qf[kd] = *reinterpret_cast<const short8*>(qp + kd * 16);
    }

    f32x16 o0, o1;
#pragma unroll
    for (int i = 0; i < 16; i++) { o0[i] = 0.f; o1[i] = 0.f; }
    float mrow = -1e30f, lrow = 0.f;

    int kt0 = 0, kt1 = 31;
    if (LOCAL) {
        kt0 = qb >= 2 ? qb - 2 : 0;
        kt1 = qb + 2 < 31 ? qb + 2 : 31;
    }
    const int NT = (kt1 - kt0 + 4) >> 2;   // ceil(n/4), uniform across WG

    // staging: 128 threads per kt-stream (waves 2kg, 2kg+1)
    const int t128 = tid & 127;
    const int r0 = t128 >> 3, c0 = (t128 & 7) * 8;   // rows r0+16j, 16B chunk c0
    const ushort_t* Kg = QKV + (size_t)(b * 2048) * 3072 + coff + 512 + h * 64;
    const ushort_t* Vg = VT + (size_t)(LOCAL ? 0 : 1) * 2097152 + (size_t)(bh * 64) * 2048;

    auto stage = [&](int kt) {
        const ushort_t* kp = Kg + (size_t)(kt * 64) * 3072;
        const ushort_t* vp = Vg + kt * 64;
        short8 kl[4], vl[4];
#pragma unroll
        for (int j = 0; j < 4; j++) {
            kl[j] = *reinterpret_cast<const short8*>(kp + (size_t)(r0 + 16 * j) * 3072 + c0);
            vl[j] = *reinterpret_cast<const short8*>(vp + (size_t)(r0 + 16 * j) * 2048 + c0);
        }
#pragma unroll
        for (int j = 0; j < 4; j++) {
            *reinterpret_cast<short8*>(&Kc[(r0 + 16 * j) * 72 + c0]) = kl[j];
            *reinterpret_cast<short8*>(&Vc[(r0 + 16 * j) * 72 + c0]) = vl[j];
        }
    };

    auto tile_step = [&](int kt) {
        f32x16 s0, s1;
#pragma unroll
        for (int i = 0; i < 16; i++) { s0[i] = 0.f; s1[i] = 0.f; }
        __builtin_amdgcn_s_setprio(1);
#pragma unroll
        for (int kd = 0; kd < 4; kd++) {
            short8 kf0 = *reinterpret_cast<const short8*>(&Kc[l31 * 72 + kd * 16 + hi * 8]);
            short8 kf1 = *reinterpret_cast<const short8*>(&Kc[(32 + l31) * 72 + kd * 16 + hi * 8]);
            s0 = MFMA32(kf0, qf[kd], s0, 0, 0, 0);
            s1 = MFMA32(kf1, qf[kd], s1, 0, 0, 0);
        }
        __builtin_amdgcn_s_setprio(0);
        if (LOCAL) {
#pragma unroll
            for (int r = 0; r < 16; r++) {
                int k0 = kt * 64 + (r & 3) + 8 * (r >> 2) + 4 * hi;
                int d0 = qrow - k0; d0 = d0 < 0 ? -d0 : d0;
                int d1 = qrow - (k0 + 32); d1 = d1 < 0 ? -d1 : d1;
                if (d0 > 128) s0[r] = -2e30f;
                if (d1 > 128) s1[r] = -2e30f;
            }
        }
        float pmax = -2e30f;
#pragma unroll
        for (int r = 0; r < 16; r++) pmax = fmaxf(pmax, fmaxf(s0[r], s1[r]));
        pmax = fmaxf(pmax, __shfl_xor(pmax, 32));
        if (!__all(pmax <= mrow + 8.f)) {
            float mnew = fmaxf(mrow, pmax);
            float sc = EXP2R(mrow - mnew);
            lrow *= sc;
#pragma unroll
            for (int r = 0; r < 16; r++) {
                int qo = (r & 3) + 8 * (r >> 2) + 4 * hi;
                float scv = __shfl(sc, qo);
                o0[r] *= scv; o1[r] *= scv;
            }
            mrow = mnew;
        }
        float ps0 = 0.f, ps1 = 0.f;
        uint32_t pk0[8], pk1[8];
#pragma unroll
        for (int i = 0; i < 8; i++) {
            float a0 = EXP2R(s0[2 * i] - mrow), b0 = EXP2R(s0[2 * i + 1] - mrow);
            float a1 = EXP2R(s1[2 * i] - mrow), b1 = EXP2R(s1[2 * i + 1] - mrow);
            ps0 += a0 + b0; ps1 += a1 + b1;
            pk0[i] = cvtpk(a0, b0);
            pk1[i] = cvtpk(a1, b1);
        }
        float psum = ps0 + ps1;
        psum += __shfl_xor(psum, 32);
        lrow += psum;

        __builtin_amdgcn_s_setprio(1);
#pragma unroll
        for (int kb = 0; kb < 2; kb++) {
#pragma unroll
            for (int m = 0; m < 2; m++) {
                uint32_t e0 = kb ? pk1[4 * m + 0] : pk0[4 * m + 0];
                uint32_t e1 = kb ? pk1[4 * m + 1] : pk0[4 * m + 1];
                uint32_t e2 = kb ? pk1[4 * m + 2] : pk0[4 * m + 2];
                uint32_t e3 = kb ? pk1[4 * m + 3] : pk0[4 * m + 3];
                auto w02 = __builtin_amdgcn_permlane32_swap(e0, e2, false, false);
                auto w13 = __builtin_amdgcn_permlane32_swap(e1, e3, false, false);
                u32x4 fv;
                fv[0] = w02[0]; fv[1] = w13[0]; fv[2] = w02[1]; fv[3] = w13[1];
                short8 pf = __builtin_bit_cast(short8, fv);
                int km = kb * 2 + m;
                short8 vf0 = *reinterpret_cast<const short8*>(&Vc[l31 * 72 + km * 16 + hi * 8]);
                short8 vf1 = *reinterpret_cast<const short8*>(&Vc[(32 + l31) * 72 + km * 16 + hi * 8]);
                o0 = MFMA32(pf, vf0, o0, 0, 0, 0);
                o1 = MFMA32(pf, vf1, o1, 0, 0, 0);
            }
        }
        __builtin_amdgcn_s_setprio(0);
    };

    int kt = kt0 + kg;
    bool valid = (kt <= kt1);
    for (int i = 0; i < NT; i++) {
        if (valid) stage(kt);
        __syncthreads();                      // staging visible to both waves of stream
        if (valid) tile_step(kt);
        __syncthreads();                      // compute done before next overwrite
        kt += 4; valid = (kt <= kt1);
    }

    // ---- merge: Ob aliases pool (safe after final barrier) ----
    float* Ob = (float*)pool;                 // [8][32][68] = 69632 B <= 73728
#pragma unroll
    for (int r = 0; r < 16; r++) {
        int qo = (r & 3) + 8 * (r >> 2) + 4 * hi;
        Ob[(w * 32 + qo) * 68 + l31] = o0[r];
        Ob[(w * 32 + qo) * 68 + 32 + l31] = o1[r];
    }
    if (lane < 32) { Mm[w][l31] = mrow; Ll[w][l31] = lrow; }
    __syncthreads();

    {
        const int row = w * 8 + (lane >> 3);  // 0..63
        const int cg = lane & 7;
        const int rg2 = row >> 5, r32 = row & 31;
        float m[4], e[4];
#pragma unroll
        for (int p = 0; p < 4; p++) m[p] = Mm[rg2 + 2 * p][r32];
        float M = fmaxf(fmaxf(m[0], m[1]), fmaxf(m[2], m[3]));
        float L = 0.f;
#pragma unroll
        for (int p = 0; p < 4; p++) {
            e[p] = EXP2R(m[p] - M);
            L += Ll[rg2 + 2 * p][r32] * e[p];
        }
        float inv = 1.0f / L;
        f32x4 accA = f32x4{0.f, 0.f, 0.f, 0.f}, accB = f32x4{0.f, 0.f, 0.f, 0.f};
#pragma unroll
        for (int p = 0; p < 4; p++) {
            int slot = rg2 + 2 * p;
            accA += *reinterpret_cast<const f32x4*>(&Ob[(slot * 32 + r32) * 68 + cg * 8]) * e[p];
            accB += *reinterpret_cast<const f32x4*>(&Ob[(slot * 32 + r32) * 68 + cg * 8 + 4]) * e[p];
        }
        u32x4 fv;
        fv[0] = cvtpk(accA[0] * inv, accA[1] * inv);
        fv[1] = cvtpk(accA[2] * inv, accA[3] * inv);
        fv[2] = cvtpk(accB[0] * inv, accB[1] * inv);
        fv[3] = cvtpk(accB[2] * inv, accB[3] * inv);
        *reinterpret_cast<u32x4*>(&A2[(size_t)(b * 2048 + qb * 64 + row) * 1024 + aoff + h * 64 + cg * 8]) = fv;
    }
}

// ---------------- launcher ----------------
extern "C" void kernel_launch(void* const* d_in, const int* in_sizes, int n_in,
                              void* d_out, int out_size, void* d_ws, size_t ws_size,
                              hipStream_t stream) {
    const float* x      = (const float*)d_in[0];
    const float* wl_in  = (const float*)d_in[2];
    const float* bl_in  = (const float*)d_in[3];
    const float* wl_out = (const float*)d_in[4];
    const float* bl_out = (const float*)d_in[5];
    const float* wg_in  = (const float*)d_in[6];
    const float* bg_in  = (const float*)d_in[7];
    const float* wg_out = (const float*)d_in[8];
    const float* bg_out = (const float*)d_in[9];
    const float* gate   = (const float*)d_in[10];

    char* ws = (char*)d_ws;
    ushort_t* xb   = (ushort_t*)ws;  ws += (size_t)4096 * 512 * 2;
    ushort_t* Wqkv = (ushort_t*)ws;  ws += (size_t)3072 * 512 * 2;
    float*    bqkv = (float*)ws;     ws += (size_t)3072 * 4;
    ushort_t* QKV  = (ushort_t*)ws;  ws += (size_t)4096 * 3072 * 2;
    ushort_t* VT   = (ushort_t*)ws;  ws += (size_t)2 * 16 * 64 * 2048 * 2;
    ushort_t* A2   = (ushort_t*)ws;  ws += (size_t)4096 * 1024 * 2;
    ushort_t* W3   = (ushort_t*)ws;  ws += (size_t)512 * 1024 * 2;
    float*    b3   = (float*)ws;     ws += (size_t)512 * 4;

    prep_all<<<2048, 256, 0, stream>>>(x, wl_in, wg_in, bl_in, bg_in,
                                       wl_out, wg_out, bl_out, bg_out, gate,
                                       xb, Wqkv, bqkv, W3, b3);

    gemm_bt<4, true, true><<<dim3(32, 24), 256, 0, stream>>>(xb, Wqkv, bqkv, QKV, VT,
                                                             4096, 3072, 512);
    attn8<<<1024, 512, 0, stream>>>(QKV, VT, A2);
    gemm_bt<1, false, false><<<dim3(32, 16), 256, 0, stream>>>(A2, W3, b3, d_out, nullptr,
                                                               4096, 512, 1024);
}

// Round 16
// 96.498 us; speedup vs baseline: 1.6028x; 1.0095x over previous
//
#include <hip/hip_runtime.h>
#include <stdint.h>

typedef unsigned short ushort_t;
typedef __attribute__((ext_vector_type(8))) short short8;
typedef __attribute__((ext_vector_type(4))) float f32x4;
typedef __attribute__((ext_vector_type(16))) float f32x16;
typedef __attribute__((ext_vector_type(4))) uint32_t u32x4;
typedef __attribute__((ext_vector_type(2))) uint32_t u32x2;

#define MFMA16 __builtin_amdgcn_mfma_f32_16x16x32_bf16
#define MFMA32 __builtin_amdgcn_mfma_f32_32x32x16_bf16

// global->LDS direct (16B/lane); dest = wave-uniform base + lane*16 (m97/m104)
#define GLOAD_LDS16(gp, lp)                                                  \
    __builtin_amdgcn_global_load_lds(                                        \
        (const __attribute__((address_space(1))) void*)(gp),                 \
        (__attribute__((address_space(3))) void*)(lp), 16, 0, 0)

__device__ inline ushort_t f2bf(float f) {
    union { float f; uint32_t u; } x; x.f = f;
    uint32_t r = x.u + 0x7FFFu + ((x.u >> 16) & 1u);
    return (ushort_t)(r >> 16);
}
// single-instruction packed f32->bf16 (RNE), gfx950
__device__ inline uint32_t cvtpk(float lo, float hi) {
    uint32_t r;
    asm("v_cvt_pk_bf16_f32 %0, %1, %2" : "=v"(r) : "v"(lo), "v"(hi));
    return r;
}
#define EXP2R __builtin_amdgcn_exp2f   // raw v_exp_f32

// ---------------- fused prep: conv_x + prep_wqkv + prep_w3 ----------------
__global__ __launch_bounds__(256) void prep_all(const float* __restrict__ x,
                                                const float* __restrict__ wl_in,
                                                const float* __restrict__ wg_in,
                                                const float* __restrict__ bl_in,
                                                const float* __restrict__ bg_in,
                                                const float* __restrict__ wl_out,
                                                const float* __restrict__ wg_out,
                                                const float* __restrict__ bl_out,
                                                const float* __restrict__ bg_out,
                                                const float* __restrict__ gate,
                                                ushort_t* __restrict__ xb,
                                                ushort_t* __restrict__ Wqkv,
                                                float* __restrict__ bqkv,
                                                ushort_t* __restrict__ W3,
                                                float* __restrict__ b3) {
    const float QSC = 0.125f * 1.44269504089f;   // fold score-scale * log2(e) into Q
    int gid = blockIdx.x * 256 + threadIdx.x;
    if (gid < 262144) {                       // x -> bf16 (4096*512/8)
        int base = gid * 8;
        short8 v;
#pragma unroll
        for (int j = 0; j < 8; j++) v[j] = (short)f2bf(x[base + j]);
        *reinterpret_cast<short8*>(&xb[base]) = v;
    } else if (gid < 458752) {                // Wqkv (3072*512/8)
        int g2 = gid - 262144;
        int base = g2 * 8;
        short8 v;
#pragma unroll
        for (int j = 0; j < 8; j++) {
            int e = base + j;
            int n = e >> 9;
            int nm = n >= 1536 ? n - 1536 : n;
            float sc = (nm < 512) ? QSC : 1.0f;
            float f = (e < 1536 * 512) ? wl_in[e] : wg_in[e - 1536 * 512];
            v[j] = (short)f2bf(f * sc);
        }
        *reinterpret_cast<short8*>(&Wqkv[base]) = v;
        if (g2 < 3072) {
            int nm = g2 >= 1536 ? g2 - 1536 : g2;
            float sc = (nm < 512) ? QSC : 1.0f;
            bqkv[g2] = ((g2 < 1536) ? bl_in[g2] : bg_in[g2 - 1536]) * sc;
        }
    } else {                                  // W3 (512*1024/8)
        int g2 = gid - 458752;
        float gv = gate[0];
        int base = g2 * 8;
        short8 v;
#pragma unroll
        for (int j = 0; j < 8; j++) {
            int e = base + j;
            int n = e >> 10, k = e & 1023;
            float f = (k < 512) ? gv * wl_out[n * 512 + k]
                                : (1.0f - gv) * wg_out[n * 512 + (k - 512)];
            v[j] = (short)f2bf(f);
        }
        *reinterpret_cast<short8*>(&W3[base]) = v;
        if (g2 < 512) b3[g2] = gv * bl_out[g2] + (1.0f - gv) * bg_out[g2];
    }
}

// ---------------- GEMM: C[M][N] = A[M][K] * B[N][K]^T + bias ----------------
// m97 staging (global_load_lds x16B, linear LDS), 2-D grid (x=bm fastest):
// default round-robin XCD assignment -> XCD = bm%8 -> per-XCD A-stripe affinity
// (0.5MB L2-resident). Do NOT remap blockIdx (r14: chunked swizzle cost +6us).
// FUSE_VT: V-range columns (n in [1024,1536)+[2560,3072)) go to VT[br][dfull][l].
template<int NI, bool OUT_BF16, bool FUSE_VT>
__global__ __launch_bounds__(256) void gemm_bt(const ushort_t* __restrict__ A,
                                               const ushort_t* __restrict__ B,
                                               const float* __restrict__ bias,
                                               void* __restrict__ Cout,
                                               ushort_t* __restrict__ VTout,
                                               int M, int N, int K) {
    constexpr int TN = NI * 32;
    __shared__ __align__(16) ushort_t As[128 * 64];
    __shared__ __align__(16) ushort_t Bs[TN * 64];
    const int tid = threadIdx.x;
    const int lane = tid & 63, wid = tid >> 6;
    const int g = lane >> 4, c = lane & 15;
    const int wm = wid >> 1, wn = wid & 1;
    const int bm = blockIdx.x, bn = blockIdx.y;

    f32x4 acc[4][NI];
#pragma unroll
    for (int i = 0; i < 4; i++)
#pragma unroll
        for (int j = 0; j < NI; j++) acc[i][j] = f32x4{0.f, 0.f, 0.f, 0.f};

    for (int ks = 0; ks < K; ks += 64) {
#pragma unroll
        for (int it = 0; it < 4; it++) {           // A: 128x64 = 1024 chunks
            int idx = it * 256 + tid;
            int r = idx >> 3, ch = idx & 7;
            GLOAD_LDS16(&A[(size_t)(bm * 128 + r) * K + ks + ch * 8],
                        &As[(size_t)(idx & ~63) * 8]);
        }
#pragma unroll
        for (int it = 0; it < TN / 32; it++) {     // B: TN x 64
            int idx = it * 256 + tid;
            int r = idx >> 3, ch = idx & 7;
            GLOAD_LDS16(&B[(size_t)(bn * TN + r) * K + ks + ch * 8],
                        &Bs[(size_t)(idx & ~63) * 8]);
        }
        __syncthreads();                           // drains vmcnt (compiler)
#pragma unroll
        for (int kk = 0; kk < 2; kk++) {
            short8 a[4], b[NI];
#pragma unroll
            for (int mi = 0; mi < 4; mi++)
                a[mi] = *reinterpret_cast<const short8*>(&As[(wm * 64 + mi * 16 + c) * 64 + kk * 32 + g * 8]);
#pragma unroll
            for (int ni = 0; ni < NI; ni++)
                b[ni] = *reinterpret_cast<const short8*>(&Bs[(wn * (NI * 16) + ni * 16 + c) * 64 + kk * 32 + g * 8]);
#pragma unroll
            for (int mi = 0; mi < 4; mi++)
#pragma unroll
                for (int ni = 0; ni < NI; ni++)
                    acc[mi][ni] = MFMA16(a[mi], b[ni], acc[mi][ni], 0, 0, 0);
        }
        __syncthreads();
    }
#pragma unroll
    for (int mi = 0; mi < 4; mi++) {
#pragma unroll
        for (int ni = 0; ni < NI; ni++) {
            int n = bn * TN + wn * (NI * 16) + ni * 16 + c;
            float bv = bias[n];
            float v0 = acc[mi][ni][0] + bv;
            float v1 = acc[mi][ni][1] + bv;
            float v2 = acc[mi][ni][2] + bv;
            float v3 = acc[mi][ni][3] + bv;
            int m0 = bm * 128 + wm * 64 + mi * 16 + g * 4;
            bool isV = FUSE_VT && (n >= 1024) && (n < 1536 || n >= 2560);
            if (isV) {
                int br = n >= 1536 ? 1 : 0;
                int dfull = (br ? n - 1536 : n) - 1024;        // 0..511
                int bb = m0 >> 11, l0 = m0 & 2047;
                u32x2 pk;
                pk[0] = cvtpk(v0, v1);
                pk[1] = cvtpk(v2, v3);
                *reinterpret_cast<u32x2*>(
                    &VTout[(size_t)br * 2097152 + ((size_t)bb * 512 + dfull) * 2048 + l0]) = pk;
            } else {
                float vv[4] = {v0, v1, v2, v3};
#pragma unroll
                for (int r = 0; r < 4; r++) {
                    int m = m0 + r;
                    if (OUT_BF16) ((ushort_t*)Cout)[(size_t)m * N + n] = f2bf(vv[r]);
                    else          ((float*)Cout)[(size_t)m * N + n] = vv[r];
                }
            }
        }
    }
}

// ---------------- attention: 4 waves, 64 q-rows, 2-way kt-split, LDS merge ----------------
// r12 structure with HALF-SIZE WGs: 4 waves (2 rg x 2 kg), kt step 2, LDS 37.9KB
// -> 4 independent WGs/CU (same 4 waves/SIMD, 4 barrier domains instead of 2).
// stage/tile_step identical to r12-proven code; merge is single-level (2 partials).
// id bits: [2:0]=h (XCD slot), [7:3]=qb64, [8]=b, [9]=branch (global=0 first)
__global__ __launch_bounds__(256, 2) void attn4(const ushort_t* __restrict__ QKV,
                                                const ushort_t* __restrict__ VT,
                                                ushort_t* __restrict__ A2) {
    const int gid = blockIdx.x;
    const int h = gid & 7;
    const int qb = (gid >> 3) & 31;
    const int b = (gid >> 8) & 1;
    const bool LOCAL = gid >= 512;
    const int bh = b * 8 + h;
    const int coff = LOCAL ? 0 : 1536;
    const int aoff = LOCAL ? 0 : 512;

    const int tid = threadIdx.x, lane = tid & 63, w = tid >> 6;   // w: 0..3
    const int l31 = lane & 31, hi = lane >> 5;
    const int rg = w & 1, kg = w >> 1;                            // kg: 0..1

    __shared__ __align__(16) char pool[2 * 2 * 9216];   // 2 streams x (K,V) 64x72 ushort
    __shared__ float Mm[4][32];
    __shared__ float Ll[4][32];
    ushort_t* Kc = (ushort_t*)(pool + kg * 18432);
    ushort_t* Vc = (ushort_t*)(pool + kg * 18432 + 9216);

    const int qrow = qb * 64 + rg * 32 + l31;
    short8 qf[4];
    {
        const ushort_t* qp = QKV + (size_t)(b * 2048 + qrow) * 3072 + coff + h * 64 + hi * 8;
#pragma unroll
        for (int kd = 0; kd < 4; kd++) qf[kd] = *reinterpret_cast<const short8*>(qp + kd * 16);
    }

    f32x16 o0, o1;
#pragma unroll
    for (int i = 0; i < 16; i++) { o0[i] = 0.f; o1[i] = 0.f; }
    float mrow = -1e30f, lrow = 0.f;

    int kt0 = 0, kt1 = 31;
    if (LOCAL) {
        kt0 = qb >= 2 ? qb - 2 : 0;
        kt1 = qb + 2 < 31 ? qb + 2 : 31;
    }
    const int NT = (kt1 - kt0 + 2) >> 1;   // ceil(n/2), uniform across WG

    // staging: 128 threads per kt-stream (waves 2kg, 2kg+1)
    const int t128 = tid & 127;
    const int r0 = t128 >> 3, c0 = (t128 & 7) * 8;   // rows r0+16j, 16B chunk c0
    const ushort_t* Kg = QKV + (size_t)(b * 2048) * 3072 + coff + 512 + h * 64;
    const ushort_t* Vg = VT + (size_t)(LOCAL ? 0 : 1) * 2097152 + (size_t)(bh * 64) * 2048;

    auto stage = [&](int kt) {
        const ushort_t* kp = Kg + (size_t)(kt * 64) * 3072;
        const ushort_t* vp = Vg + kt * 64;
        short8 kl[4], vl[4];
#pragma unroll
        for (int j = 0; j < 4; j++) {
            kl[j] = *reinterpret_cast<const short8*>(kp + (size_t)(r0 + 16 * j) * 3072 + c0);
            vl[j] = *reinterpret_cast<const short8*>(vp + (size_t)(r0 + 16 * j) * 2048 + c0);
        }
#pragma unroll
        for (int j = 0; j < 4; j++) {
            *reinterpret_cast<short8*>(&Kc[(r0 + 16 * j) * 72 + c0]) = kl[j];
            *reinterpret_cast<short8*>(&Vc[(r0 + 16 * j) * 72 + c0]) = vl[j];
        }
    };

    auto tile_step = [&](int kt) {
        f32x16 s0, s1;
#pragma unroll
        for (int i = 0; i < 16; i++) { s0[i] = 0.f; s1[i] = 0.f; }
        __builtin_amdgcn_s_setprio(1);
#pragma unroll
        for (int kd = 0; kd < 4; kd++) {
            short8 kf0 = *reinterpret_cast<const short8*>(&Kc[l31 * 72 + kd * 16 + hi * 8]);
            short8 kf1 = *reinterpret_cast<const short8*>(&Kc[(32 + l31) * 72 + kd * 16 + hi * 8]);
            s0 = MFMA32(kf0, qf[kd], s0, 0, 0, 0);
            s1 = MFMA32(kf1, qf[kd], s1, 0, 0, 0);
        }
        __builtin_amdgcn_s_setprio(0);
        if (LOCAL) {
#pragma unroll
            for (int r = 0; r < 16; r++) {
                int k0 = kt * 64 + (r & 3) + 8 * (r >> 2) + 4 * hi;
                int d0 = qrow - k0; d0 = d0 < 0 ? -d0 : d0;
                int d1 = qrow - (k0 + 32); d1 = d1 < 0 ? -d1 : d1;
                if (d0 > 128) s0[r] = -2e30f;
                if (d1 > 128) s1[r] = -2e30f;
            }
        }
        float pmax = -2e30f;
#pragma unroll
        for (int r = 0; r < 16; r++) pmax = fmaxf(pmax, fmaxf(s0[r], s1[r]));
        pmax = fmaxf(pmax, __shfl_xor(pmax, 32));
        if (!__all(pmax <= mrow + 8.f)) {
            float mnew = fmaxf(mrow, pmax);
            float sc = EXP2R(mrow - mnew);
            lrow *= sc;
#pragma unroll
            for (int r = 0; r < 16; r++) {
                int qo = (r & 3) + 8 * (r >> 2) + 4 * hi;
                float scv = __shfl(sc, qo);
                o0[r] *= scv; o1[r] *= scv;
            }
            mrow = mnew;
        }
        float ps0 = 0.f, ps1 = 0.f;
        uint32_t pk0[8], pk1[8];
#pragma unroll
        for (int i = 0; i < 8; i++) {
            float a0 = EXP2R(s0[2 * i] - mrow), b0 = EXP2R(s0[2 * i + 1] - mrow);
            float a1 = EXP2R(s1[2 * i] - mrow), b1 = EXP2R(s1[2 * i + 1] - mrow);
            ps0 += a0 + b0; ps1 += a1 + b1;
            pk0[i] = cvtpk(a0, b0);
            pk1[i] = cvtpk(a1, b1);
        }
        float psum = ps0 + ps1;
        psum += __shfl_xor(psum, 32);
        lrow += psum;

        __builtin_amdgcn_s_setprio(1);
#pragma unroll
        for (int kb = 0; kb < 2; kb++) {
#pragma unroll
            for (int m = 0; m < 2; m++) {
                uint32_t e0 = kb ? pk1[4 * m + 0] : pk0[4 * m + 0];
                uint32_t e1 = kb ? pk1[4 * m + 1] : pk0[4 * m + 1];
                uint32_t e2 = kb ? pk1[4 * m + 2] : pk0[4 * m + 2];
                uint32_t e3 = kb ? pk1[4 * m + 3] : pk0[4 * m + 3];
                auto w02 = __builtin_amdgcn_permlane32_swap(e0, e2, false, false);
                auto w13 = __builtin_amdgcn_permlane32_swap(e1, e3, false, false);
                u32x4 fv;
                fv[0] = w02[0]; fv[1] = w13[0]; fv[2] = w02[1]; fv[3] = w13[1];
                short8 pf = __builtin_bit_cast(short8, fv);
                int km = kb * 2 + m;
                short8 vf0 = *reinterpret_cast<const short8*>(&Vc[l31 * 72 + km * 16 + hi * 8]);
                short8 vf1 = *reinterpret_cast<const short8*>(&Vc[(32 + l31) * 72 + km * 16 + hi * 8]);
                o0 = MFMA32(pf, vf0, o0, 0, 0, 0);
                o1 = MFMA32(pf, vf1, o1, 0, 0, 0);
            }
        }
        __builtin_amdgcn_s_setprio(0);
    };

    int kt = kt0 + kg;
    bool valid = (kt <= kt1);
    for (int i = 0; i < NT; i++) {
        if (valid) stage(kt);
        __syncthreads();                      // staging visible to both waves of stream
        if (valid) tile_step(kt);
        __syncthreads();                      // compute done before next overwrite
        kt += 2; valid = (kt <= kt1);
    }

    // ---- single-level merge: waves 2-3 (kg=1) publish; waves 0-1 combine+write ----
    float* Ob = (float*)pool;                 // [2][32][68] f32 = 17408 B <= 36864
    if (w >= 2) {
        const int slot = w - 2;               // == rg of publisher
#pragma unroll
        for (int r = 0; r < 16; r++) {
            int qo = (r & 3) + 8 * (r >> 2) + 4 * hi;
            Ob[(slot * 32 + qo) * 68 + l31] = o0[r];
            Ob[(slot * 32 + qo) * 68 + 32 + l31] = o1[r];
        }
        if (lane < 32) { Mm[w][l31] = mrow; Ll[w][l31] = lrow; }
    }
    __syncthreads();
    if (w < 2) {                              // rg == w
        float mb = Mm[w + 2][l31], lb = Ll[w + 2][l31];
        float M = fmaxf(mrow, mb);
        float ea = EXP2R(mrow - M), eb = EXP2R(mb - M);
        float lfin = lrow * ea + lb * eb;
        float inv = 1.0f / lfin;
#pragma unroll
        for (int r = 0; r < 16; r++) {
            int qo = (r & 3) + 8 * (r >> 2) + 4 * hi;
            float sa = __shfl(ea, qo), sb = __shfl(eb, qo);
            float iv = __shfl(inv, qo);
            float v0 = o0[r] * sa + Ob[(w * 32 + qo) * 68 + l31] * sb;
            float v1 = o1[r] * sa + Ob[(w * 32 + qo) * 68 + 32 + l31] * sb;
            size_t rowb = (size_t)(b * 2048 + qb * 64 + w * 32 + qo) * 1024 + aoff + h * 64;
            A2[rowb + l31] = f2bf(v0 * iv);
            A2[rowb + 32 + l31] = f2bf(v1 * iv);
        }
    }
}

// ---------------- launcher ----------------
extern "C" void kernel_launch(void* const* d_in, const int* in_sizes, int n_in,
                              void* d_out, int out_size, void* d_ws, size_t ws_size,
                              hipStream_t stream) {
    const float* x      = (const float*)d_in[0];
    const float* wl_in  = (const float*)d_in[2];
    const float* bl_in  = (const float*)d_in[3];
    const float* wl_out = (const float*)d_in[4];
    const float* bl_out = (const float*)d_in[5];
    const float* wg_in  = (const float*)d_in[6];
    const float* bg_in  = (const float*)d_in[7];
    const float* wg_out = (const float*)d_in[8];
    const float* bg_out = (const float*)d_in[9];
    const float* gate   = (const float*)d_in[10];

    char* ws = (char*)d_ws;
    ushort_t* xb   = (ushort_t*)ws;  ws += (size_t)4096 * 512 * 2;
    ushort_t* Wqkv = (ushort_t*)ws;  ws += (size_t)3072 * 512 * 2;
    float*    bqkv = (float*)ws;     ws += (size_t)3072 * 4;
    ushort_t* QKV  = (ushort_t*)ws;  ws += (size_t)4096 * 3072 * 2;
    ushort_t* VT   = (ushort_t*)ws;  ws += (size_t)2 * 16 * 64 * 2048 * 2;
    ushort_t* A2   = (ushort_t*)ws;  ws += (size_t)4096 * 1024 * 2;
    ushort_t* W3   = (ushort_t*)ws;  ws += (size_t)512 * 1024 * 2;
    float*    b3   = (float*)ws;     ws += (size_t)512 * 4;

    prep_all<<<2048, 256, 0, stream>>>(x, wl_in, wg_in, bl_in, bg_in,
                                       wl_out, wg_out, bl_out, bg_out, gate,
                                       xb, Wqkv, bqkv, W3, b3);

    gemm_bt<4, true, true><<<dim3(32, 24), 256, 0, stream>>>(xb, Wqkv, bqkv, QKV, VT,
                                                             4096, 3072, 512);
    attn4<<<1024, 256, 0, stream>>>(QKV, VT, A2);
    gemm_bt<1, false, false><<<dim3(32, 16), 256, 0, stream>>>(A2, W3, b3, d_out, nullptr,
                                                               4096, 512, 1024);
}

// Round 17
// 96.163 us; speedup vs baseline: 1.6084x; 1.0035x over previous
//
#include <hip/hip_runtime.h>
#include <stdint.h>

typedef unsigned short ushort_t;
typedef __attribute__((ext_vector_type(8))) short short8;
typedef __attribute__((ext_vector_type(4))) float f32x4;
typedef __attribute__((ext_vector_type(16))) float f32x16;
typedef __attribute__((ext_vector_type(4))) uint32_t u32x4;
typedef __attribute__((ext_vector_type(2))) uint32_t u32x2;

#define MFMA16 __builtin_amdgcn_mfma_f32_16x16x32_bf16
#define MFMA32 __builtin_amdgcn_mfma_f32_32x32x16_bf16

// global->LDS direct (16B/lane); dest = wave-uniform base + lane*16 (m97/m104)
#define GLOAD_LDS16(gp, lp)                                                  \
    __builtin_amdgcn_global_load_lds(                                        \
        (const __attribute__((address_space(1))) void*)(gp),                 \
        (__attribute__((address_space(3))) void*)(lp), 16, 0, 0)

__device__ inline ushort_t f2bf(float f) {
    union { float f; uint32_t u; } x; x.f = f;
    uint32_t r = x.u + 0x7FFFu + ((x.u >> 16) & 1u);
    return (ushort_t)(r >> 16);
}
// single-instruction packed f32->bf16 (RNE), gfx950
__device__ inline uint32_t cvtpk(float lo, float hi) {
    uint32_t r;
    asm("v_cvt_pk_bf16_f32 %0, %1, %2" : "=v"(r) : "v"(lo), "v"(hi));
    return r;
}
#define EXP2R __builtin_amdgcn_exp2f   // raw v_exp_f32

// ---------------- fused prep: conv_x + prep_wqkv + prep_w3 ----------------
__global__ __launch_bounds__(256) void prep_all(const float* __restrict__ x,
                                                const float* __restrict__ wl_in,
                                                const float* __restrict__ wg_in,
                                                const float* __restrict__ bl_in,
                                                const float* __restrict__ bg_in,
                                                const float* __restrict__ wl_out,
                                                const float* __restrict__ wg_out,
                                                const float* __restrict__ bl_out,
                                                const float* __restrict__ bg_out,
                                                const float* __restrict__ gate,
                                                ushort_t* __restrict__ xb,
                                                ushort_t* __restrict__ Wqkv,
                                                float* __restrict__ bqkv,
                                                ushort_t* __restrict__ W3,
                                                float* __restrict__ b3) {
    const float QSC = 0.125f * 1.44269504089f;   // fold score-scale * log2(e) into Q
    int gid = blockIdx.x * 256 + threadIdx.x;
    if (gid < 262144) {                       // x -> bf16 (4096*512/8)
        int base = gid * 8;
        short8 v;
#pragma unroll
        for (int j = 0; j < 8; j++) v[j] = (short)f2bf(x[base + j]);
        *reinterpret_cast<short8*>(&xb[base]) = v;
    } else if (gid < 458752) {                // Wqkv (3072*512/8)
        int g2 = gid - 262144;
        int base = g2 * 8;
        short8 v;
#pragma unroll
        for (int j = 0; j < 8; j++) {
            int e = base + j;
            int n = e >> 9;
            int nm = n >= 1536 ? n - 1536 : n;
            float sc = (nm < 512) ? QSC : 1.0f;
            float f = (e < 1536 * 512) ? wl_in[e] : wg_in[e - 1536 * 512];
            v[j] = (short)f2bf(f * sc);
        }
        *reinterpret_cast<short8*>(&Wqkv[base]) = v;
        if (g2 < 3072) {
            int nm = g2 >= 1536 ? g2 - 1536 : g2;
            float sc = (nm < 512) ? QSC : 1.0f;
            bqkv[g2] = ((g2 < 1536) ? bl_in[g2] : bg_in[g2 - 1536]) * sc;
        }
    } else {                                  // W3 (512*1024/8)
        int g2 = gid - 458752;
        float gv = gate[0];
        int base = g2 * 8;
        short8 v;
#pragma unroll
        for (int j = 0; j < 8; j++) {
            int e = base + j;
            int n = e >> 10, k = e & 1023;
            float f = (k < 512) ? gv * wl_out[n * 512 + k]
                                : (1.0f - gv) * wg_out[n * 512 + (k - 512)];
            v[j] = (short)f2bf(f);
        }
        *reinterpret_cast<short8*>(&W3[base]) = v;
        if (g2 < 512) b3[g2] = gv * bl_out[g2] + (1.0f - gv) * bg_out[g2];
    }
}

// ---------------- QKV GEMM (32x32x16 MFMA): C[M][N] = A*B^T + bias ----------------
// Block 128x128, 4 waves (2x2), wave = 64x64 as 2x2 tiles of 32x32.
// MFMA32: A-op lane holds A[row=l31][k=hi*8+e]; B-op lane holds B^T[n=l31][k] (verified
// end-to-end by the attention kernel's QK^T since r4). C/D: col=l31, row=(r&3)+8(r>>2)+4hi.
// m97 staging (global_load_lds x16B, linear LDS). 2-D grid (x=bm): default round-robin
// gives XCD=bm%8 A-stripe L2 affinity (r14: do NOT remap).
// FUSE_VT epilogue: V-cols (n in [1024,1536)+[2560,3072)) -> VT[br][dfull][l].
__global__ __launch_bounds__(256) void gemm32_qkv(const ushort_t* __restrict__ A,
                                                  const ushort_t* __restrict__ B,
                                                  const float* __restrict__ bias,
                                                  ushort_t* __restrict__ Cout,
                                                  ushort_t* __restrict__ VTout) {
    const int K = 512, N = 3072;
    __shared__ __align__(16) ushort_t As[128 * 64];
    __shared__ __align__(16) ushort_t Bs[128 * 64];
    const int tid = threadIdx.x;
    const int lane = tid & 63, wid = tid >> 6;
    const int l31 = lane & 31, hi = lane >> 5;
    const int wm = wid >> 1, wn = wid & 1;
    const int bm = blockIdx.x, bn = blockIdx.y;

    f32x16 acc00, acc01, acc10, acc11;
#pragma unroll
    for (int i = 0; i < 16; i++) { acc00[i] = 0.f; acc01[i] = 0.f; acc10[i] = 0.f; acc11[i] = 0.f; }

    for (int ks = 0; ks < K; ks += 64) {
#pragma unroll
        for (int it = 0; it < 4; it++) {           // A: 128x64 = 1024 x 16B chunks
            int idx = it * 256 + tid;
            int r = idx >> 3, ch = idx & 7;
            GLOAD_LDS16(&A[(size_t)(bm * 128 + r) * K + ks + ch * 8],
                        &As[(size_t)(idx & ~63) * 8]);
        }
#pragma unroll
        for (int it = 0; it < 4; it++) {           // B: 128x64
            int idx = it * 256 + tid;
            int r = idx >> 3, ch = idx & 7;
            GLOAD_LDS16(&B[(size_t)(bn * 128 + r) * K + ks + ch * 8],
                        &Bs[(size_t)(idx & ~63) * 8]);
        }
        __syncthreads();                           // drains vmcnt (compiler)
#pragma unroll
        for (int kk = 0; kk < 4; kk++) {           // K-slices of 16
            short8 a0 = *reinterpret_cast<const short8*>(&As[(wm * 64 + l31) * 64 + kk * 16 + hi * 8]);
            short8 a1 = *reinterpret_cast<const short8*>(&As[(wm * 64 + 32 + l31) * 64 + kk * 16 + hi * 8]);
            short8 b0 = *reinterpret_cast<const short8*>(&Bs[(wn * 64 + l31) * 64 + kk * 16 + hi * 8]);
            short8 b1 = *reinterpret_cast<const short8*>(&Bs[(wn * 64 + 32 + l31) * 64 + kk * 16 + hi * 8]);
            acc00 = MFMA32(a0, b0, acc00, 0, 0, 0);
            acc01 = MFMA32(a0, b1, acc01, 0, 0, 0);
            acc10 = MFMA32(a1, b0, acc10, 0, 0, 0);
            acc11 = MFMA32(a1, b1, acc11, 0, 0, 0);
        }
        __syncthreads();
    }
    // epilogue (named accs, compile-time indices only — rule #20)
    auto epi = [&](const f32x16& ac, int mt, int nt) {
        int n = bn * 128 + wn * 64 + nt * 32 + l31;
        float bv = bias[n];
        bool isV = (n >= 1024) && (n < 1536 || n >= 2560);
        int br = n >= 1536 ? 1 : 0;
        int dfull = (br ? n - 1536 : n) - 1024;    // valid only when isV
#pragma unroll
        for (int q = 0; q < 4; q++) {
            float v0 = ac[4 * q + 0] + bv;
            float v1 = ac[4 * q + 1] + bv;
            float v2 = ac[4 * q + 2] + bv;
            float v3 = ac[4 * q + 3] + bv;
            int m0 = bm * 128 + wm * 64 + mt * 32 + 8 * q + 4 * hi;   // rows m0..m0+3
            if (isV) {
                int bb = m0 >> 11, l0 = m0 & 2047;
                u32x2 pk;
                pk[0] = cvtpk(v0, v1);
                pk[1] = cvtpk(v2, v3);
                *reinterpret_cast<u32x2*>(
                    &VTout[(size_t)br * 2097152 + ((size_t)bb * 512 + dfull) * 2048 + l0]) = pk;
            } else {
                Cout[(size_t)(m0 + 0) * N + n] = f2bf(v0);
                Cout[(size_t)(m0 + 1) * N + n] = f2bf(v1);
                Cout[(size_t)(m0 + 2) * N + n] = f2bf(v2);
                Cout[(size_t)(m0 + 3) * N + n] = f2bf(v3);
            }
        }
    };
    epi(acc00, 0, 0); epi(acc01, 0, 1); epi(acc10, 1, 0); epi(acc11, 1, 1);
}

// ---------------- out-GEMM (16x16x32 MFMA, unchanged r15): C = A*B^T + bias ----------------
template<int NI, bool OUT_BF16>
__global__ __launch_bounds__(256) void gemm_bt(const ushort_t* __restrict__ A,
                                               const ushort_t* __restrict__ B,
                                               const float* __restrict__ bias,
                                               void* __restrict__ Cout,
                                               int M, int N, int K) {
    constexpr int TN = NI * 32;
    __shared__ __align__(16) ushort_t As[128 * 64];
    __shared__ __align__(16) ushort_t Bs[TN * 64];
    const int tid = threadIdx.x;
    const int lane = tid & 63, wid = tid >> 6;
    const int g = lane >> 4, c = lane & 15;
    const int wm = wid >> 1, wn = wid & 1;
    const int bm = blockIdx.x, bn = blockIdx.y;

    f32x4 acc[4][NI];
#pragma unroll
    for (int i = 0; i < 4; i++)
#pragma unroll
        for (int j = 0; j < NI; j++) acc[i][j] = f32x4{0.f, 0.f, 0.f, 0.f};

    for (int ks = 0; ks < K; ks += 64) {
#pragma unroll
        for (int it = 0; it < 4; it++) {           // A: 128x64 = 1024 chunks
            int idx = it * 256 + tid;
            int r = idx >> 3, ch = idx & 7;
            GLOAD_LDS16(&A[(size_t)(bm * 128 + r) * K + ks + ch * 8],
                        &As[(size_t)(idx & ~63) * 8]);
        }
#pragma unroll
        for (int it = 0; it < TN / 32; it++) {     // B: TN x 64
            int idx = it * 256 + tid;
            int r = idx >> 3, ch = idx & 7;
            GLOAD_LDS16(&B[(size_t)(bn * TN + r) * K + ks + ch * 8],
                        &Bs[(size_t)(idx & ~63) * 8]);
        }
        __syncthreads();                           // drains vmcnt (compiler)
#pragma unroll
        for (int kk = 0; kk < 2; kk++) {
            short8 a[4], b[NI];
#pragma unroll
            for (int mi = 0; mi < 4; mi++)
                a[mi] = *reinterpret_cast<const short8*>(&As[(wm * 64 + mi * 16 + c) * 64 + kk * 32 + g * 8]);
#pragma unroll
            for (int ni = 0; ni < NI; ni++)
                b[ni] = *reinterpret_cast<const short8*>(&Bs[(wn * (NI * 16) + ni * 16 + c) * 64 + kk * 32 + g * 8]);
#pragma unroll
            for (int mi = 0; mi < 4; mi++)
#pragma unroll
                for (int ni = 0; ni < NI; ni++)
                    acc[mi][ni] = MFMA16(a[mi], b[ni], acc[mi][ni], 0, 0, 0);
        }
        __syncthreads();
    }
#pragma unroll
    for (int mi = 0; mi < 4; mi++) {
#pragma unroll
        for (int ni = 0; ni < NI; ni++) {
            int n = bn * TN + wn * (NI * 16) + ni * 16 + c;
            float bv = bias[n];
#pragma unroll
            for (int r = 0; r < 4; r++) {
                int m = bm * 128 + wm * 64 + mi * 16 + g * 4 + r;
                float v = acc[mi][ni][r] + bv;
                if (OUT_BF16) ((ushort_t*)Cout)[(size_t)m * N + n] = f2bf(v);
                else          ((float*)Cout)[(size_t)m * N + n] = v;
            }
        }
    }
}

// ---------------- attention: 4 waves, 64 q-rows, 2-way kt-split, LDS merge ----------------
// r16-proven (<=42.4us): 72-pad LDS, reg-staged stage(), 2 barriers/iter, 4 WGs/CU.
// (r7/r13: forcing occupancy spills; r9: prefetch ILP loses to TLP; r11: gload banks.)
// id bits: [2:0]=h (XCD slot), [7:3]=qb64, [8]=b, [9]=branch (global=0 first)
__global__ __launch_bounds__(256, 2) void attn4(const ushort_t* __restrict__ QKV,
                                                const ushort_t* __restrict__ VT,
                                                ushort_t* __restrict__ A2) {
    const int gid = blockIdx.x;
    const int h = gid & 7;
    const int qb = (gid >> 3) & 31;
    const int b = (gid >> 8) & 1;
    const bool LOCAL = gid >= 512;
    const int bh = b * 8 + h;
    const int coff = LOCAL ? 0 : 1536;
    const int aoff = LOCAL ? 0 : 512;

    const int tid = threadIdx.x, lane = tid & 63, w = tid >> 6;   // w: 0..3
    const int l31 = lane & 31, hi = lane >> 5;
    const int rg = w & 1, kg = w >> 1;                            // kg: 0..1

    __shared__ __align__(16) char pool[2 * 2 * 9216];   // 2 streams x (K,V) 64x72 ushort
    __shared__ float Mm[4][32];
    __shared__ float Ll[4][32];
    ushort_t* Kc = (ushort_t*)(pool + kg * 18432);
    ushort_t* Vc = (ushort_t*)(pool + kg * 18432 + 9216);

    const int qrow = qb * 64 + rg * 32 + l31;
    short8 qf[4];
    {
        const ushort_t* qp = QKV + (size_t)(b * 2048 + qrow) * 3072 + coff + h * 64 + hi * 8;
#pragma unroll
        for (int kd = 0; kd < 4; kd++) qf[kd] = *reinterpret_cast<const short8*>(qp + kd * 16);
    }

    f32x16 o0, o1;
#pragma unroll
    for (int i = 0; i < 16; i++) { o0[i] = 0.f; o1[i] = 0.f; }
    float mrow = -1e30f, lrow = 0.f;

    int kt0 = 0, kt1 = 31;
    if (LOCAL) {
        kt0 = qb >= 2 ? qb - 2 : 0;
        kt1 = qb + 2 < 31 ? qb + 2 : 31;
    }
    const int NT = (kt1 - kt0 + 2) >> 1;   // ceil(n/2), uniform across WG

    // staging: 128 threads per kt-stream (waves 2kg, 2kg+1)
    const int t128 = tid & 127;
    const int r0 = t128 >> 3, c0 = (t128 & 7) * 8;   // rows r0+16j, 16B chunk c0
    const ushort_t* Kg = QKV + (size_t)(b * 2048) * 3072 + coff + 512 + h * 64;
    const ushort_t* Vg = VT + (size_t)(LOCAL ? 0 : 1) * 2097152 + (size_t)(bh * 64) * 2048;

    auto stage = [&](int kt) {
        const ushort_t* kp = Kg + (size_t)(kt * 64) * 3072;
        const ushort_t* vp = Vg + kt * 64;
        short8 kl[4], vl[4];
#pragma unroll
        for (int j = 0; j < 4; j++) {
            kl[j] = *reinterpret_cast<const short8*>(kp + (size_t)(r0 + 16 * j) * 3072 + c0);
            vl[j] = *reinterpret_cast<const short8*>(vp + (size_t)(r0 + 16 * j) * 2048 + c0);
        }
#pragma unroll
        for (int j = 0; j < 4; j++) {
            *reinterpret_cast<short8*>(&Kc[(r0 + 16 * j) * 72 + c0]) = kl[j];
            *reinterpret_cast<short8*>(&Vc[(r0 + 16 * j) * 72 + c0]) = vl[j];
        }
    };

    auto tile_step = [&](int kt) {
        f32x16 s0, s1;
#pragma unroll
        for (int i = 0; i < 16; i++) { s0[i] = 0.f; s1[i] = 0.f; }
        __builtin_amdgcn_s_setprio(1);
#pragma unroll
        for (int kd = 0; kd < 4; kd++) {
            short8 kf0 = *reinterpret_cast<const short8*>(&Kc[l31 * 72 + kd * 16 + hi * 8]);
            short8 kf1 = *reinterpret_cast<const short8*>(&Kc[(32 + l31) * 72 + kd * 16 + hi * 8]);
            s0 = MFMA32(kf0, qf[kd], s0, 0, 0, 0);
            s1 = MFMA32(kf1, qf[kd], s1, 0, 0, 0);
        }
        __builtin_amdgcn_s_setprio(0);
        if (LOCAL) {
#pragma unroll
            for (int r = 0; r < 16; r++) {
                int k0 = kt * 64 + (r & 3) + 8 * (r >> 2) + 4 * hi;
                int d0 = qrow - k0; d0 = d0 < 0 ? -d0 : d0;
                int d1 = qrow - (k0 + 32); d1 = d1 < 0 ? -d1 : d1;
                if (d0 > 128) s0[r] = -2e30f;
                if (d1 > 128) s1[r] = -2e30f;
            }
        }
        float pmax = -2e30f;
#pragma unroll
        for (int r = 0; r < 16; r++) pmax = fmaxf(pmax, fmaxf(s0[r], s1[r]));
        pmax = fmaxf(pmax, __shfl_xor(pmax, 32));
        if (!__all(pmax <= mrow + 8.f)) {
            float mnew = fmaxf(mrow, pmax);
            float sc = EXP2R(mrow - mnew);
            lrow *= sc;
#pragma unroll
            for (int r = 0; r < 16; r++) {
                int qo = (r & 3) + 8 * (r >> 2) + 4 * hi;
                float scv = __shfl(sc, qo);
                o0[r] *= scv; o1[r] *= scv;
            }
            mrow = mnew;
        }
        float ps0 = 0.f, ps1 = 0.f;
        uint32_t pk0[8], pk1[8];
#pragma unroll
        for (int i = 0; i < 8; i++) {
            float a0 = EXP2R(s0[2 * i] - mrow), b0 = EXP2R(s0[2 * i + 1] - mrow);
            float a1 = EXP2R(s1[2 * i] - mrow), b1 = EXP2R(s1[2 * i + 1] - mrow);
            ps0 += a0 + b0; ps1 += a1 + b1;
            pk0[i] = cvtpk(a0, b0);
            pk1[i] = cvtpk(a1, b1);
        }
        float psum = ps0 + ps1;
        psum += __shfl_xor(psum, 32);
        lrow += psum;

        __builtin_amdgcn_s_setprio(1);
#pragma unroll
        for (int kb = 0; kb < 2; kb++) {
#pragma unroll
            for (int m = 0; m < 2; m++) {
                uint32_t e0 = kb ? pk1[4 * m + 0] : pk0[4 * m + 0];
                uint32_t e1 = kb ? pk1[4 * m + 1] : pk0[4 * m + 1];
                uint32_t e2 = kb ? pk1[4 * m + 2] : pk0[4 * m + 2];
                uint32_t e3 = kb ? pk1[4 * m + 3] : pk0[4 * m + 3];
                auto w02 = __builtin_amdgcn_permlane32_swap(e0, e2, false, false);
                auto w13 = __builtin_amdgcn_permlane32_swap(e1, e3, false, false);
                u32x4 fv;
                fv[0] = w02[0]; fv[1] = w13[0]; fv[2] = w02[1]; fv[3] = w13[1];
                short8 pf = __builtin_bit_cast(short8, fv);
                int km = kb * 2 + m;
                short8 vf0 = *reinterpret_cast<const short8*>(&Vc[l31 * 72 + km * 16 + hi * 8]);
                short8 vf1 = *reinterpret_cast<const short8*>(&Vc[(32 + l31) * 72 + km * 16 + hi * 8]);
                o0 = MFMA32(pf, vf0, o0, 0, 0, 0);
                o1 = MFMA32(pf, vf1, o1, 0, 0, 0);
            }
        }
        __builtin_amdgcn_s_setprio(0);
    };

    int kt = kt0 + kg;
    bool valid = (kt <= kt1);
    for (int i = 0; i < NT; i++) {
        if (valid) stage(kt);
        __syncthreads();                      // staging visible to both waves of stream
        if (valid) tile_step(kt);
        __syncthreads();                      // compute done before next overwrite
        kt += 2; valid = (kt <= kt1);
    }

    // ---- single-level merge: waves 2-3 (kg=1) publish; waves 0-1 combine+write ----
    float* Ob = (float*)pool;                 // [2][32][68] f32 = 17408 B <= 36864
    if (w >= 2) {
        const int slot = w - 2;               // == rg of publisher
#pragma unroll
        for (int r = 0; r < 16; r++) {
            int qo = (r & 3) + 8 * (r >> 2) + 4 * hi;
            Ob[(slot * 32 + qo) * 68 + l31] = o0[r];
            Ob[(slot * 32 + qo) * 68 + 32 + l31] = o1[r];
        }
        if (lane < 32) { Mm[w][l31] = mrow; Ll[w][l31] = lrow; }
    }
    __syncthreads();
    if (w < 2) {                              // rg == w
        float mb = Mm[w + 2][l31], lb = Ll[w + 2][l31];
        float M = fmaxf(mrow, mb);
        float ea = EXP2R(mrow - M), eb = EXP2R(mb - M);
        float lfin = lrow * ea + lb * eb;
        float inv = 1.0f / lfin;
#pragma unroll
        for (int r = 0; r < 16; r++) {
            int qo = (r & 3) + 8 * (r >> 2) + 4 * hi;
            float sa = __shfl(ea, qo), sb = __shfl(eb, qo);
            float iv = __shfl(inv, qo);
            float v0 = o0[r] * sa + Ob[(w * 32 + qo) * 68 + l31] * sb;
            float v1 = o1[r] * sa + Ob[(w * 32 + qo) * 68 + 32 + l31] * sb;
            size_t rowb = (size_t)(b * 2048 + qb * 64 + w * 32 + qo) * 1024 + aoff + h * 64;
            A2[rowb + l31] = f2bf(v0 * iv);
            A2[rowb + 32 + l31] = f2bf(v1 * iv);
        }
    }
}

// ---------------- launcher ----------------
extern "C" void kernel_launch(void* const* d_in, const int* in_sizes, int n_in,
                              void* d_out, int out_size, void* d_ws, size_t ws_size,
                              hipStream_t stream) {
    const float* x      = (const float*)d_in[0];
    const float* wl_in  = (const float*)d_in[2];
    const float* bl_in  = (const float*)d_in[3];
    const float* wl_out = (const float*)d_in[4];
    const float* bl_out = (const float*)d_in[5];
    const float* wg_in  = (const float*)d_in[6];
    const float* bg_in  = (const float*)d_in[7];
    const float* wg_out = (const float*)d_in[8];
    const float* bg_out = (const float*)d_in[9];
    const float* gate   = (const float*)d_in[10];

    char* ws = (char*)d_ws;
    ushort_t* xb   = (ushort_t*)ws;  ws += (size_t)4096 * 512 * 2;
    ushort_t* Wqkv = (ushort_t*)ws;  ws += (size_t)3072 * 512 * 2;
    float*    bqkv = (float*)ws;     ws += (size_t)3072 * 4;
    ushort_t* QKV  = (ushort_t*)ws;  ws += (size_t)4096 * 3072 * 2;
    ushort_t* VT   = (ushort_t*)ws;  ws += (size_t)2 * 16 * 64 * 2048 * 2;
    ushort_t* A2   = (ushort_t*)ws;  ws += (size_t)4096 * 1024 * 2;
    ushort_t* W3   = (ushort_t*)ws;  ws += (size_t)512 * 1024 * 2;
    float*    b3   = (float*)ws;     ws += (size_t)512 * 4;

    prep_all<<<2048, 256, 0, stream>>>(x, wl_in, wg_in, bl_in, bg_in,
                                       wl_out, wg_out, bl_out, bg_out, gate,
                                       xb, Wqkv, bqkv, W3, b3);

    gemm32_qkv<<<dim3(32, 24), 256, 0, stream>>>(xb, Wqkv, bqkv, QKV, VT);
    attn4<<<1024, 256, 0, stream>>>(QKV, VT, A2);
    gemm_bt<1, false><<<dim3(32, 16), 256, 0, stream>>>(A2, W3, b3, d_out,
                                                        4096, 512, 1024);
}